// Round 16
// baseline (1090.891 us; speedup 1.0000x reference)
//
#include <hip/hip_runtime.h>
#include <math.h>

#define DEV static __device__ __forceinline__

typedef __attribute__((ext_vector_type(8))) short short8v;
typedef __attribute__((ext_vector_type(8))) _Float16 half8v;
typedef __attribute__((ext_vector_type(4))) float f32x4;

// ---------- helpers ----------
DEV unsigned encf(float f){ unsigned b=__float_as_uint(f); return b ^ (0x80000000u | (unsigned)((int)b>>31)); }
DEV unsigned long long pkvi(float v, int idx){
  return ((unsigned long long)encf(v)<<32) | (unsigned long long)(0xffffffffu - (unsigned)idx);
}
DEV unsigned long long wave_max_ull(unsigned long long u){
  #pragma unroll
  for (int m=1;m<64;m<<=1){ unsigned long long o = __shfl_xor(u, m); if (o>u) u=o; }
  return u;
}
DEV float wave_sum(float v){
  #pragma unroll
  for (int m=32;m;m>>=1) v += __shfl_xor(v, m);
  return v;
}
DEV float blk_sum256(float v, float* scr){
  v = wave_sum(v);
  __syncthreads();
  if ((threadIdx.x & 63)==0) scr[threadIdx.x>>6] = v;
  __syncthreads();
  return scr[0]+scr[1]+scr[2]+scr[3];
}
DEV float gelu_f(float x){ return 0.5f*x*(1.f + tanhf(0.7978845608028654f*(x + 0.044715f*x*x*x))); }
DEV unsigned short f2bf(float x){
  unsigned u = __float_as_uint(x);
  unsigned r = (u + 0x7fffu + ((u>>16)&1u)) >> 16;
  return (unsigned short)r;
}
DEV float bf2f(unsigned short h){ return __uint_as_float(((unsigned)h)<<16); }
DEV void gld16(const void* g, void* l){
  __builtin_amdgcn_global_load_lds((const __attribute__((address_space(1))) unsigned int*)g,
                                   (__attribute__((address_space(3))) unsigned int*)l, 16, 0, 0);
}
template<int CTRL>
DEV float dppf(float x){
  return __int_as_float(__builtin_amdgcn_mov_dpp(__float_as_int(x), CTRL, 0xF, 0xF, false));
}

// ---------- weight pre-conversion: fp32 W[R][C] -> bf16 hi/lo [n][k] ----------
template<bool TRANS, bool SUBI>
__global__ __launch_bounds__(256) void k_convw(const float* __restrict__ W,
    unsigned short* __restrict__ hi, unsigned short* __restrict__ lo, int R, int C){
  int n = blockIdx.x;
  int K = TRANS ? R : C;
  for (int k = threadIdx.x; k < K; k += 256){
    float x = TRANS ? W[(size_t)k*C + n] : W[(size_t)n*C + k];
    if (SUBI && k==n) x -= 1.f;
    unsigned short h = f2bf(x);
    hi[(size_t)n*K + k] = h;
    if (lo) lo[(size_t)n*K + k] = f2bf(x - bf2f(h));
  }
}

// ---------- fused conversion of 4 transposed 512x512 weights ----------
__global__ __launch_bounds__(256) void k_convw4(
  const float* __restrict__ Wq, const float* __restrict__ Wk,
  const float* __restrict__ Wv, const float* __restrict__ Wo,
  unsigned short* __restrict__ qh, unsigned short* __restrict__ ql,
  unsigned short* __restrict__ kh, unsigned short* __restrict__ kl,
  unsigned short* __restrict__ vh, unsigned short* __restrict__ vl,
  unsigned short* __restrict__ oh, unsigned short* __restrict__ ol)
{
  int n = blockIdx.x;
  const float* W; unsigned short *hi, *lo;
  switch(blockIdx.y){
    case 0: W=Wq; hi=qh; lo=ql; break;
    case 1: W=Wk; hi=kh; lo=kl; break;
    case 2: W=Wv; hi=vh; lo=vl; break;
    default: W=Wo; hi=oh; lo=ol; break;
  }
  for (int k = threadIdx.x; k < 512; k += 256){
    float x = W[(size_t)k*512 + n];
    unsigned short h = f2bf(x);
    hi[(size_t)n*512 + k] = h;
    lo[(size_t)n*512 + k] = f2bf(x - bf2f(h));
  }
}

// ---------- D = Wa - I as f16 in MFMA-fragment-major layout ----------
__global__ __launch_bounds__(256) void k_convd2(const float* __restrict__ Wa, unsigned short* __restrict__ Dfrag){
  int e = blockIdx.x;
  int tile = e>>4, lr = e&15;
  for (int d = threadIdx.x; d < 512; d += 256){
    float x = Wa[(size_t)e*512 + d] - (e==d ? 1.f : 0.f);
    union { _Float16 hh; unsigned short u; } cv;
    cv.hh = (_Float16)x;
    int ks = d>>5, q = (d>>3)&3, el = d&7;
    Dfrag[(size_t)(((tile*16+ks)*64 + q*16 + lr)*8 + el)] = cv.u;
  }
}

// ---------- gemmAB: both operands pre-converted bf16 hi/lo, gld16 staging ----------
// EPI bits: 1=+bias[n], 2=gelu, 4=+resid fp32, 8=write hi/lo (else fp32)
template<int EPI>
__global__ __launch_bounds__(256,2) void gemmAB(
  const unsigned short* __restrict__ Ahi, const unsigned short* __restrict__ Alo,
  const unsigned short* __restrict__ Bhi, const unsigned short* __restrict__ Blo,
  float* __restrict__ Cp, unsigned short* __restrict__ Chi, unsigned short* __restrict__ Clo,
  const int M, const int N, const int K,
  const float* __restrict__ bias, const float* __restrict__ resid)
{
  __shared__ __align__(16) char sm[32768];
  const int t = threadIdx.x, lane = t&63, wid = t>>6;
  const int row0 = blockIdx.x*128, col0 = blockIdx.y*128;
  f32x4 acc[2][8];
  #pragma unroll
  for (int i=0;i<2;++i)
    #pragma unroll
    for (int j=0;j<8;++j) acc[i][j] = (f32x4){0.f,0.f,0.f,0.f};

  int offA[2], offB[8];
  #pragma unroll
  for (int mt=0; mt<2; ++mt){
    int row = (2*wid+mt)*16 + (lane&15);
    int sp = (lane>>4) ^ ((row>>1)&3);
    offA[mt] = row*64 + sp*16;
  }
  #pragma unroll
  for (int nt=0; nt<8; ++nt){
    int row = nt*16 + (lane&15);
    int sp = (lane>>4) ^ ((row>>1)&3);
    offB[nt] = row*64 + sp*16;
  }

  const int nks = K >> 5;
  for (int ks=0; ks<nks; ++ks){
    #pragma unroll
    for (int i=0;i<2;++i){
      int s = i*256 + t, row = s>>2, sl2 = s&3, slog = sl2 ^ ((row>>1)&3);
      size_t ga = (size_t)(row0+row)*K + ks*32 + slog*8;
      size_t gb = (size_t)(col0+row)*K + ks*32 + slog*8;
      int dst = (i*256 + wid*64)*16;
      gld16(Ahi + ga, sm + dst);
      gld16(Alo + ga, sm + 8192 + dst);
      gld16(Bhi + gb, sm + 16384 + dst);
      gld16(Blo + gb, sm + 24576 + dst);
    }
    __syncthreads();
    short8v ah0 = *(short8v*)(sm + offA[0]);
    short8v ah1 = *(short8v*)(sm + offA[1]);
    short8v al0 = *(short8v*)(sm + 8192 + offA[0]);
    short8v al1 = *(short8v*)(sm + 8192 + offA[1]);
    #pragma unroll
    for (int nt=0; nt<8; ++nt){
      short8v bh = *(short8v*)(sm + 16384 + offB[nt]);
      short8v bl = *(short8v*)(sm + 24576 + offB[nt]);
      acc[0][nt] = __builtin_amdgcn_mfma_f32_16x16x32_bf16(ah0, bh, acc[0][nt], 0,0,0);
      acc[0][nt] = __builtin_amdgcn_mfma_f32_16x16x32_bf16(ah0, bl, acc[0][nt], 0,0,0);
      acc[0][nt] = __builtin_amdgcn_mfma_f32_16x16x32_bf16(al0, bh, acc[0][nt], 0,0,0);
      acc[1][nt] = __builtin_amdgcn_mfma_f32_16x16x32_bf16(ah1, bh, acc[1][nt], 0,0,0);
      acc[1][nt] = __builtin_amdgcn_mfma_f32_16x16x32_bf16(ah1, bl, acc[1][nt], 0,0,0);
      acc[1][nt] = __builtin_amdgcn_mfma_f32_16x16x32_bf16(al1, bh, acc[1][nt], 0,0,0);
    }
    __syncthreads();
  }

  #pragma unroll
  for (int mt=0; mt<2; ++mt){
    #pragma unroll
    for (int nt=0; nt<8; ++nt){
      int n = col0 + nt*16 + (lane&15);
      int mb = row0 + (2*wid+mt)*16 + (lane>>4)*4;
      #pragma unroll
      for (int j=0;j<4;++j){
        int m = mb + j;
        if (m < M){
          float v = acc[mt][nt][j];
          if (EPI & 1) v += bias[n];
          if (EPI & 2) v = gelu_f(v);
          if (EPI & 4) v += resid[(size_t)m*N + n];
          if (EPI & 8){
            unsigned short h = f2bf(v);
            Chi[(size_t)m*N + n] = h;
            Clo[(size_t)m*N + n] = f2bf(v - bf2f(h));
          } else {
            Cp[(size_t)m*N + n] = v;
          }
        }
      }
    }
  }
}

// ---------- fused QKV on pre-converted A (z selector) ----------
__global__ __launch_bounds__(256,2) void gemmABQKV(
  const unsigned short* __restrict__ lnH, const unsigned short* __restrict__ lnL,
  const unsigned short* __restrict__ tkH, const unsigned short* __restrict__ tkL,
  const unsigned short* __restrict__ qh, const unsigned short* __restrict__ ql,
  const unsigned short* __restrict__ kh, const unsigned short* __restrict__ kl,
  const unsigned short* __restrict__ vh, const unsigned short* __restrict__ vl,
  float* __restrict__ qb, float* __restrict__ kb, float* __restrict__ vbuf)
{
  __shared__ __align__(16) char sm[32768];
  const int z = blockIdx.z;
  const unsigned short* Ahi = (z==0)? lnH : tkH;
  const unsigned short* Alo = (z==0)? lnL : tkL;
  const unsigned short* Bhi = (z==0)? qh : (z==1? kh : vh);
  const unsigned short* Blo = (z==0)? ql : (z==1? kl : vl);
  float* Cp = (z==0)? qb : (z==1? kb : vbuf);
  const int M = (z==0)? 1632 : 1600;
  const int K = 512, N = 512;
  const int t = threadIdx.x, lane = t&63, wid = t>>6;
  const int row0 = blockIdx.x*128, col0 = blockIdx.y*128;
  f32x4 acc[2][8];
  #pragma unroll
  for (int i=0;i<2;++i)
    #pragma unroll
    for (int j=0;j<8;++j) acc[i][j] = (f32x4){0.f,0.f,0.f,0.f};

  int offA[2], offB[8];
  #pragma unroll
  for (int mt=0; mt<2; ++mt){
    int row = (2*wid+mt)*16 + (lane&15);
    int sp = (lane>>4) ^ ((row>>1)&3);
    offA[mt] = row*64 + sp*16;
  }
  #pragma unroll
  for (int nt=0; nt<8; ++nt){
    int row = nt*16 + (lane&15);
    int sp = (lane>>4) ^ ((row>>1)&3);
    offB[nt] = row*64 + sp*16;
  }

  for (int ks=0; ks<16; ++ks){
    #pragma unroll
    for (int i=0;i<2;++i){
      int s = i*256 + t, row = s>>2, sl2 = s&3, slog = sl2 ^ ((row>>1)&3);
      size_t ga = (size_t)(row0+row)*K + ks*32 + slog*8;
      size_t gb = (size_t)(col0+row)*K + ks*32 + slog*8;
      int dst = (i*256 + wid*64)*16;
      gld16(Ahi + ga, sm + dst);
      gld16(Alo + ga, sm + 8192 + dst);
      gld16(Bhi + gb, sm + 16384 + dst);
      gld16(Blo + gb, sm + 24576 + dst);
    }
    __syncthreads();
    short8v ah0 = *(short8v*)(sm + offA[0]);
    short8v ah1 = *(short8v*)(sm + offA[1]);
    short8v al0 = *(short8v*)(sm + 8192 + offA[0]);
    short8v al1 = *(short8v*)(sm + 8192 + offA[1]);
    #pragma unroll
    for (int nt=0; nt<8; ++nt){
      short8v bh = *(short8v*)(sm + 16384 + offB[nt]);
      short8v bl = *(short8v*)(sm + 24576 + offB[nt]);
      acc[0][nt] = __builtin_amdgcn_mfma_f32_16x16x32_bf16(ah0, bh, acc[0][nt], 0,0,0);
      acc[0][nt] = __builtin_amdgcn_mfma_f32_16x16x32_bf16(ah0, bl, acc[0][nt], 0,0,0);
      acc[0][nt] = __builtin_amdgcn_mfma_f32_16x16x32_bf16(al0, bh, acc[0][nt], 0,0,0);
      acc[1][nt] = __builtin_amdgcn_mfma_f32_16x16x32_bf16(ah1, bh, acc[1][nt], 0,0,0);
      acc[1][nt] = __builtin_amdgcn_mfma_f32_16x16x32_bf16(ah1, bl, acc[1][nt], 0,0,0);
      acc[1][nt] = __builtin_amdgcn_mfma_f32_16x16x32_bf16(al1, bh, acc[1][nt], 0,0,0);
    }
    __syncthreads();
  }

  #pragma unroll
  for (int mt=0; mt<2; ++mt){
    #pragma unroll
    for (int nt=0; nt<8; ++nt){
      int n = col0 + nt*16 + (lane&15);
      int mb = row0 + (2*wid+mt)*16 + (lane>>4)*4;
      #pragma unroll
      for (int j=0;j<4;++j){
        int m = mb + j;
        if (m < M) Cp[(size_t)m*N + n] = acc[mt][nt][j];
      }
    }
  }
}

// ---------- cache path v10: ks-interleaved stage||MFMA pipeline, panel-resident ----------
__global__ __launch_bounds__(512,1) void k_un7(
  const float* __restrict__ raw, const unsigned short* __restrict__ Dfrag,
  const float* __restrict__ zm, const int* __restrict__ clab,
  float* __restrict__ cdot, float* __restrict__ norm2)
{
  __shared__ __align__(16) char Alds[131072];
  __shared__ float n2sq[128];
  __shared__ float n2x[4][128];
  const int t = threadIdx.x, lane = t&63;
  const int wid = t>>6, wm = wid>>2, wn = wid&3;
  const int m0 = blockIdx.x*128;

  const int row = t>>2, sl = t&3;
  const int slg = sl ^ ((row>>1)&3);
  const float* rp = raw + ((size_t)(m0+row))*512 + slg*8;
  const float* zp = zm + (size_t)clab[(m0+row)/196]*512 + slg*8;

  int offA[4];
  #pragma unroll
  for (int mt=0; mt<4; ++mt){
    int r2 = wm*64 + mt*16 + (lane&15);
    int sp = (lane>>4) ^ ((r2>>1)&3);
    offA[mt] = r2*64 + sp*16;
  }
  const half8v* Dv = (const half8v*)Dfrag;

  // accumulators for all 4 e-blocks: [eb][mt][nt]
  f32x4 acc[4][4][2];
  #pragma unroll
  for (int eb=0;eb<4;++eb)
    #pragma unroll
    for (int mt=0;mt<4;++mt)
      #pragma unroll
      for (int nt=0;nt<2;++nt) acc[eb][mt][nt] = (f32x4){0.f,0.f,0.f,0.f};

  float sq=0.f, cd=0.f;
  float4 lr[16][2], lz[16][2];
  // prologue: prefetch ks = 0, 1
  #pragma unroll
  for (int k0=0;k0<2;++k0){
    lr[k0][0] = *(const float4*)(rp + k0*32);
    lr[k0][1] = *(const float4*)(rp + k0*32 + 4);
    lz[k0][0] = *(const float4*)(zp + k0*32);
    lz[k0][1] = *(const float4*)(zp + k0*32 + 4);
  }

  #pragma unroll
  for (int ks=0; ks<16; ++ks){
    // prefetch ks+2 (in flight across this iteration's convert+barrier+MFMA)
    if (ks+2 < 16){
      lr[ks+2][0] = *(const float4*)(rp + (ks+2)*32);
      lr[ks+2][1] = *(const float4*)(rp + (ks+2)*32 + 4);
      lz[ks+2][0] = *(const float4*)(zp + (ks+2)*32);
      lz[ks+2][1] = *(const float4*)(zp + (ks+2)*32 + 4);
    }
    // convert + stage tile ks (+ fused exact fp32 sq/cdot)
    {
      float xs[8] = {lr[ks][0].x,lr[ks][0].y,lr[ks][0].z,lr[ks][0].w,
                     lr[ks][1].x,lr[ks][1].y,lr[ks][1].z,lr[ks][1].w};
      float zs[8] = {lz[ks][0].x,lz[ks][0].y,lz[ks][0].z,lz[ks][0].w,
                     lz[ks][1].x,lz[ks][1].y,lz[ks][1].z,lz[ks][1].w};
      union { _Float16 h[8]; f32x4 f; } uh;
      #pragma unroll
      for (int u=0;u<8;++u){
        uh.h[u] = (_Float16)xs[u];
        sq = fmaf(xs[u],xs[u],sq);
        cd = fmaf(xs[u],zs[u],cd);
      }
      *(f32x4*)(Alds + ks*8192 + t*16) = uh.f;
    }
    __syncthreads();
    // MFMA tile ks for all 4 e-blocks (loads for ks+1/ks+2 still in flight)
    half8v af[4];
    #pragma unroll
    for (int mt=0; mt<4; ++mt) af[mt] = *(half8v*)(Alds + ks*8192 + offA[mt]);
    #pragma unroll
    for (int eb=0;eb<4;++eb){
      #pragma unroll
      for (int nt=0;nt<2;++nt){
        half8v bf = Dv[(size_t)(((eb*8 + wn*2 + nt)*16 + ks)*64 + lane)];
        #pragma unroll
        for (int mt=0;mt<4;++mt)
          acc[eb][mt][nt] = __builtin_amdgcn_mfma_f32_16x16x32_f16(af[mt], bf, acc[eb][mt][nt], 0,0,0);
      }
    }
  }

  // sq/cd reduce + writes
  sq += __shfl_xor(sq,1); sq += __shfl_xor(sq,2);
  cd += __shfl_xor(cd,1); cd += __shfl_xor(cd,2);
  if (sl==0){ n2sq[row] = sq; cdot[m0+row] = cd; }

  // epilogue: cross-terms for all e-blocks from resident panel
  float pacc[4][4];
  #pragma unroll
  for (int a_=0;a_<4;++a_)
    #pragma unroll
    for (int b_=0;b_<4;++b_) pacc[a_][b_]=0.f;

  #pragma unroll
  for (int eb=0; eb<4; ++eb){
    #pragma unroll
    for (int mt=0; mt<4; ++mt){
      #pragma unroll
      for (int j=0;j<4;++j){
        int row2 = wm*64 + mt*16 + (lane>>4)*4 + j;
        float p = 0.f;
        #pragma unroll
        for (int nt=0; nt<2; ++nt){
          float U = acc[eb][mt][nt][j];
          int eg = eb*128 + wn*32 + nt*16 + (lane&15);
          int kse = eg>>5, o = eg&31;
          int sll = (o>>3) ^ ((row2>>1)&3);
          float rh = (float)*(const _Float16*)(Alds + kse*8192 + row2*64 + sll*16 + (o&7)*2);
          p = fmaf(U, 2.f*rh + U, p);
        }
        p += __shfl_xor(p,1); p += __shfl_xor(p,2); p += __shfl_xor(p,4); p += __shfl_xor(p,8);
        pacc[mt][j] += p;
      }
    }
  }

  // combine across wn waves, single deterministic write
  __syncthreads();
  if ((lane&15)==0){
    #pragma unroll
    for (int mt=0; mt<4; ++mt)
      #pragma unroll
      for (int j=0;j<4;++j)
        n2x[wn][wm*64 + mt*16 + (lane>>4)*4 + j] = pacc[mt][j];
  }
  __syncthreads();
  if (t < 128)
    norm2[m0+t] = n2sq[t] + n2x[0][t] + n2x[1][t] + n2x[2][t] + n2x[3][t];
}

// ---------- row normalize (512 cols), optional bf16 dual-write ----------
__global__ __launch_bounds__(256) void k_rownorm(const float* __restrict__ in, float* __restrict__ out,
                                                 unsigned short* __restrict__ bfo, int nrows){
  __shared__ float scr[4];
  int r = blockIdx.x, t = threadIdx.x; (void)nrows;
  const float* p = in + (size_t)r*512;
  float x0 = p[t], x1 = p[t+256];
  float ss = blk_sum256(x0*x0 + x1*x1, scr);
  float inv = 1.f/sqrtf(ss);
  float v0 = x0*inv, v1 = x1*inv;
  out[(size_t)r*512 + t] = v0;
  out[(size_t)r*512 + t + 256] = v1;
  if (bfo){
    size_t br = (size_t)(r/196)*256 + (r%196);
    bfo[br*512 + t]     = f2bf(v0);
    bfo[br*512 + t+256] = f2bf(v1);
  }
}

// ---------- mean over consecutive rows, then normalize ----------
__global__ __launch_bounds__(256) void k_meanrows_norm(const float* __restrict__ in, int nper,
                                                       float* __restrict__ o1, float* __restrict__ o2){
  __shared__ float scr[4];
  int g = blockIdx.x, t = threadIdx.x;
  float s0=0.f, s1=0.f;
  const float* bp = in + (size_t)g*nper*512;
  for (int r=0;r<nper;++r){ s0 += bp[(size_t)r*512+t]; s1 += bp[(size_t)r*512+t+256]; }
  float ss = blk_sum256(s0*s0+s1*s1, scr);
  float inv = 1.f/sqrtf(ss);
  float v0 = s0*inv, v1 = s1*inv;
  o1[(size_t)g*512+t]=v0; o1[(size_t)g*512+t+256]=v1;
  if (o2){ o2[(size_t)g*512+t]=v0; o2[(size_t)g*512+t+256]=v1; }
}

// ---------- z = btm @ Wa ----------
__global__ __launch_bounds__(256) void k_zmat(const float* __restrict__ btm, const float* __restrict__ Wa, float* __restrict__ z){
  int c = blockIdx.x, t = threadIdx.x;
  float a0=0.f, a1=0.f;
  for (int d=0; d<512; ++d){
    float bv = btm[c*512+d];
    a0 = fmaf(bv, Wa[(size_t)d*512+t], a0);
    a1 = fmaf(bv, Wa[(size_t)d*512+t+256], a1);
  }
  z[c*512+t]=a0; z[c*512+t+256]=a1;
}

// ---------- per-(b,p) row dot with a per-b 512-vector ----------
__global__ __launch_bounds__(256) void k_dot_bp(const float* __restrict__ AL, const float* __restrict__ vecs,
                                                const int* __restrict__ sel, float* __restrict__ outv, int mode){
  int wid = blockIdx.x*4 + (threadIdx.x>>6);
  int lane = threadIdx.x & 63;
  int b = wid/196;
  int vrow = sel ? sel[b] : (mode ? 0 : b);
  const float* a = AL + (size_t)wid*512 + lane*8;
  const float* v = vecs + (size_t)vrow*512 + lane*8;
  float4 a0 = *(const float4*)a, a1 = *(const float4*)(a+4);
  float4 v0 = *(const float4*)v, v1 = *(const float4*)(v+4);
  float s = a0.x*v0.x + a0.y*v0.y + a0.z*v0.z + a0.w*v0.w
          + a1.x*v1.x + a1.y*v1.y + a1.z*v1.z + a1.w*v1.w;
  s = wave_sum(s);
  if (lane==0) outv[wid] = s;
}

// ---------- fused dual dot ----------
__global__ __launch_bounds__(256) void k_dot2(const float* __restrict__ AL, const float* __restrict__ AGw,
                                              const float* __restrict__ RN00,
                                              float* __restrict__ wbp, float* __restrict__ sLw){
  int wid = blockIdx.x*4 + (threadIdx.x>>6);
  int lane = threadIdx.x & 63;
  int b = wid/196;
  const float* a = AL + (size_t)wid*512 + lane*8;
  const float* v = AGw + (size_t)b*512 + lane*8;
  const float* w = RN00 + lane*8;
  float4 a0=*(const float4*)a, a1=*(const float4*)(a+4);
  float4 v0=*(const float4*)v, v1=*(const float4*)(v+4);
  float4 w0=*(const float4*)w, w1=*(const float4*)(w+4);
  float s1 = a0.x*v0.x+a0.y*v0.y+a0.z*v0.z+a0.w*v0.w + a1.x*v1.x+a1.y*v1.y+a1.z*v1.z+a1.w*v1.w;
  float s2 = a0.x*w0.x+a0.y*w0.y+a0.z*w0.z+a0.w*w0.w + a1.x*w1.x+a1.y*w1.y+a1.z*w1.z+a1.w*w1.w;
  s1 = wave_sum(s1); s2 = wave_sum(s2);
  if (lane==0){ wbp[wid] = s1; sLw[wid] = s2; }
}

// ---------- sorted top-50 and bottom-50 indices of st[b,:196] ----------
__global__ __launch_bounds__(64) void k_topbot(const float* __restrict__ st, int* __restrict__ tki, int* __restrict__ bki){
  int b = blockIdx.x, lane = threadIdx.x;
  float v[4];
  #pragma unroll
  for (int s2=0;s2<4;++s2){ int p = lane + 64*s2; v[s2] = (p<196)? st[b*196+p] : -INFINITY; }
  for (int k=0;k<50;++k){
    unsigned long long best = pkvi(v[0], lane);
    { unsigned long long cc=pkvi(v[1],lane+64);  if(cc>best)best=cc; }
    { unsigned long long cc=pkvi(v[2],lane+128); if(cc>best)best=cc; }
    { unsigned long long cc=pkvi(v[3],lane+192); if(cc>best)best=cc; }
    best = wave_max_ull(best);
    int widx = (int)(0xffffffffu - (unsigned)(best & 0xffffffffu));
    if (lane==0) tki[b*50+k] = widx;
    if ((widx & 63)==lane) v[widx>>6] = -INFINITY;
  }
  #pragma unroll
  for (int s2=0;s2<4;++s2){ int p = lane + 64*s2; v[s2] = (p<196)? -st[b*196+p] : -INFINITY; }
  for (int k=0;k<50;++k){
    unsigned long long best = pkvi(v[0], lane);
    { unsigned long long cc=pkvi(v[1],lane+64);  if(cc>best)best=cc; }
    { unsigned long long cc=pkvi(v[2],lane+128); if(cc>best)best=cc; }
    { unsigned long long cc=pkvi(v[3],lane+192); if(cc>best)best=cc; }
    best = wave_max_ull(best);
    int widx = (int)(0xffffffffu - (unsigned)(best & 0xffffffffu));
    if (lane==0) bki[b*50+k] = widx;
    if ((widx & 63)==lane) v[widx>>6] = -INFINITY;
  }
}

// ---------- gather topk/botk feats (+ bf16 hi/lo of topk), query_keys ----------
__global__ __launch_bounds__(256) void k_gather_tb(const float* __restrict__ AL, const int* __restrict__ tki, const int* __restrict__ bki,
                                                   float* __restrict__ otk, float* __restrict__ obk, float* __restrict__ qk,
                                                   unsigned short* __restrict__ tkH, unsigned short* __restrict__ tkL){
  __shared__ float scr[4];
  int b = blockIdx.x, t = threadIdx.x;
  float a0=0.f, a1=0.f;
  for (int k=0;k<50;++k){
    int pt = tki[b*50+k];
    const float* rp = AL + ((size_t)b*196+pt)*512;
    float x0 = rp[t], x1 = rp[t+256];
    size_t ro = ((size_t)b*50+k)*512;
    otk[ro + t] = x0; otk[ro + t+256] = x1;
    unsigned short h0 = f2bf(x0), h1 = f2bf(x1);
    tkH[ro + t] = h0;      tkL[ro + t]     = f2bf(x0 - bf2f(h0));
    tkH[ro + t+256] = h1;  tkL[ro + t+256] = f2bf(x1 - bf2f(h1));
    a0 += x0; a1 += x1;
    int pb = bki[b*50+k];
    const float* rb = AL + ((size_t)b*196+pb)*512;
    obk[ro + t] = rb[t]; obk[ro + t+256] = rb[t+256];
  }
  float ss = blk_sum256(a0*a0+a1*a1, scr);
  float inv = 1.f/sqrtf(ss);
  qk[b*512+t] = a0*inv; qk[b*512+t+256] = a1*inv;
}

// ---------- fused gather x = text_cache[labels] + layernorm -> xb fp32, ln1 hi/lo ----------
__global__ __launch_bounds__(256) void k_gxln(const float* __restrict__ tc, const int* __restrict__ labels,
                                              const float* __restrict__ g, const float* __restrict__ be,
                                              float* __restrict__ xb,
                                              unsigned short* __restrict__ hi, unsigned short* __restrict__ lo){
  __shared__ float scr[4];
  int r = blockIdx.x, t = threadIdx.x;
  int b = r/51, n = r%51;
  int lab = labels[b];
  const float* src = tc + ((size_t)lab*51 + n)*512;
  float x0 = src[t], x1 = src[t+256];
  xb[(size_t)r*512+t] = x0; xb[(size_t)r*512+t+256] = x1;
  float s = blk_sum256(x0+x1, scr);
  float mean = s*(1.f/512.f);
  float ss = blk_sum256(x0*x0+x1*x1, scr);
  float var = ss*(1.f/512.f) - mean*mean;
  float inv = 1.f/sqrtf(var + 1e-5f);
  float v0 = (x0-mean)*inv*g[t]     + be[t];
  float v1 = (x1-mean)*inv*g[t+256] + be[t+256];
  unsigned short h0 = f2bf(v0), h1 = f2bf(v1);
  hi[(size_t)r*512+t]     = h0;  lo[(size_t)r*512+t]     = f2bf(v0 - bf2f(h0));
  hi[(size_t)r*512+t+256] = h1;  lo[(size_t)r*512+t+256] = f2bf(v1 - bf2f(h1));
}

// ---------- layernorm over 512, bf16 hi/lo output ----------
__global__ __launch_bounds__(256) void k_layernorm2(const float* __restrict__ in,
                                                    unsigned short* __restrict__ hi, unsigned short* __restrict__ lo,
                                                    const float* __restrict__ g, const float* __restrict__ be){
  __shared__ float scr[4];
  int r = blockIdx.x, t = threadIdx.x;
  const float* p = in + (size_t)r*512;
  float x0=p[t], x1=p[t+256];
  float s = blk_sum256(x0+x1, scr);
  float mean = s*(1.f/512.f);
  float ss = blk_sum256(x0*x0+x1*x1, scr);
  float var = ss*(1.f/512.f) - mean*mean;
  float inv = 1.f/sqrtf(var + 1e-5f);
  float v0 = (x0-mean)*inv*g[t]     + be[t];
  float v1 = (x1-mean)*inv*g[t+256] + be[t+256];
  unsigned short h0 = f2bf(v0), h1 = f2bf(v1);
  hi[(size_t)r*512+t]     = h0;  lo[(size_t)r*512+t]     = f2bf(v0 - bf2f(h0));
  hi[(size_t)r*512+t+256] = h1;  lo[(size_t)r*512+t+256] = f2bf(v1 - bf2f(h1));
}

// ---------- bonder attention, bf16 hi/lo output ----------
__global__ __launch_bounds__(256) void k_attn2(const float* __restrict__ qb, const float* __restrict__ kb,
                                               const float* __restrict__ vb,
                                               unsigned short* __restrict__ obH, unsigned short* __restrict__ obL){
  int b = blockIdx.x, h = blockIdx.y, t = threadIdx.x;
  __shared__ float qh[51][65];
  __shared__ float kh[50][65];
  __shared__ float vh[50][65];
  __shared__ float S[51][52];
  for (int f=t; f<51*64; f+=256){ int n=f>>6, d=f&63; qh[n][d] = qb[((size_t)(b*51+n))*512 + h*64 + d]; }
  for (int f=t; f<50*64; f+=256){ int m=f>>6, d=f&63;
    kh[m][d] = kb[((size_t)(b*50+m))*512 + h*64 + d];
    vh[m][d] = vb[((size_t)(b*50+m))*512 + h*64 + d];
  }
  __syncthreads();
  for (int f=t; f<51*50; f+=256){
    int n=f/50, m=f%50;
    float s=0.f;
    #pragma unroll 8
    for (int d=0; d<64; ++d) s = fmaf(qh[n][d], kh[m][d], s);
    S[n][m] = s*0.125f;
  }
  __syncthreads();
  int w = t>>6, lane = t&63;
  for (int n=w; n<51; n+=4){
    float x = (lane<50)? S[n][lane] : -INFINITY;
    float mx = x;
    #pragma unroll
    for (int m2=32;m2;m2>>=1) mx = fmaxf(mx, __shfl_xor(mx,m2));
    float e = (lane<50)? expf(x-mx) : 0.f;
    float se = wave_sum(e);
    if (lane<50) S[n][lane] = e/se;
  }
  __syncthreads();
  for (int f=t; f<51*64; f+=256){
    int n=f>>6, d=f&63;
    float s=0.f;
    #pragma unroll 10
    for (int m=0;m<50;++m) s = fmaf(S[n][m], vh[m][d], s);
    size_t idx = ((size_t)(b*51+n))*512 + h*64 + d;
    unsigned short hh = f2bf(s);
    obH[idx] = hh; obL[idx] = f2bf(s - bf2f(hh));
  }
}

// ---------- refined_norm row (c,n), dual-write bf16 padded ----------
__global__ __launch_bounds__(256) void k_refined(const float* __restrict__ tc, const float* __restrict__ TB,
                                                 const int* __restrict__ labels, float* __restrict__ RN,
                                                 unsigned short* __restrict__ RNbf){
  __shared__ float scr[4];
  __shared__ int labL[32];
  int blk = blockIdx.x, t = threadIdx.x;
  int c = blk/51, n = blk%51;
  if (t<32) labL[t] = labels[t];
  __syncthreads();
  float r0=0.f, r1=0.f;
  for (int b=0;b<32;++b){
    if (labL[b]==c){
      const float* tb = TB + ((size_t)(b*51+n))*512;
      r0 += tb[t]; r1 += tb[t+256];
    }
  }
  const float* tcp = tc + ((size_t)(c*51+n))*512;
  r0 = tcp[t]     + r0*(1.f/64.f);
  r1 = tcp[t+256] + r1*(1.f/64.f);
  float ss = blk_sum256(r0*r0+r1*r1, scr);
  float inv = 1.f/sqrtf(ss);
  float v0 = r0*inv, v1 = r1*inv;
  RN[((size_t)(c*51+n))*512+t]     = v0;
  RN[((size_t)(c*51+n))*512+t+256] = v1;
  size_t br = (size_t)c*64 + n;
  RNbf[br*512 + t]     = f2bf(v0);
  RNbf[br*512 + t+256] = f2bf(v1);
}

// ---------- v softmax ----------
__global__ __launch_bounds__(256) void k_vsm(const float* __restrict__ RN, const float* __restrict__ RMN, float* __restrict__ vsm){
  __shared__ float sv[51];
  int c = blockIdx.x, t = threadIdx.x, w = t>>6, lane = t&63;
  for (int n=w; n<51; n+=4){
    const float* a = RN + ((size_t)(c*51+n))*512 + lane*8;
    const float* m = RMN + (size_t)c*512 + lane*8;
    float4 a0=*(const float4*)a, a1=*(const float4*)(a+4);
    float4 m0=*(const float4*)m, m1=*(const float4*)(m+4);
    float s = a0.x*m0.x+a0.y*m0.y+a0.z*m0.z+a0.w*m0.w + a1.x*m1.x+a1.y*m1.y+a1.z*m1.z+a1.w*m1.w;
    s = wave_sum(s);
    if (lane==0) sv[n]=s;
  }
  __syncthreads();
  if (t<64){
    float x = (t<51)? sv[t] : -INFINITY;
    float mx = x;
    #pragma unroll
    for (int m2=32;m2;m2>>=1) mx = fmaxf(mx, __shfl_xor(mx,m2));
    float e = (t<51)? expf(x-mx) : 0.f;
    float se = wave_sum(e);
    if (t<51) vsm[c*51+t] = e/se;
  }
}

// ---------- idx_w -> w_topk per b ----------
__global__ __launch_bounds__(64) void k_wtopk(const float* __restrict__ sLg,
                                              const float* __restrict__ wbp, float* __restrict__ wtk){
  __shared__ int idxL[50];
  int b = blockIdx.x, lane = threadIdx.x;
  float v[4];
  #pragma unroll
  for (int s2=0;s2<4;++s2){ int p = lane+64*s2; v[s2] = (p<196)? sLg[b*196+p] : -INFINITY; }
  for (int k=0;k<50;++k){
    unsigned long long best = pkvi(v[0], lane);
    { unsigned long long cc=pkvi(v[1],lane+64);  if(cc>best)best=cc; }
    { unsigned long long cc=pkvi(v[2],lane+128); if(cc>best)best=cc; }
    { unsigned long long cc=pkvi(v[3],lane+192); if(cc>best)best=cc; }
    best = wave_max_ull(best);
    int widx = (int)(0xffffffffu - (unsigned)(best & 0xffffffffu));
    if (lane==0) idxL[k]=widx;
    if ((widx&63)==lane) v[widx>>6] = -INFINITY;
  }
  __syncthreads();
  float wv = (lane<50)? wbp[b*196 + idxL[lane]] : -INFINITY;
  float mx = wv;
  #pragma unroll
  for (int m2=32;m2;m2>>=1) mx = fmaxf(mx, __shfl_xor(mx,m2));
  float e = (lane<50)? expf(wv-mx) : 0.f;
  float se = wave_sum(e);
  if (lane<50) wtk[b*50+lane] = e/se;
}

// ---------- dense logits v3: dbuf MFMA GEMM + register bitonic top-50 ----------
__global__ __launch_bounds__(256,3) void k_dense3(
  const unsigned short* __restrict__ ALbf, const unsigned short* __restrict__ RNbf,
  const float* __restrict__ RMN, const float* __restrict__ AG,
  const float* __restrict__ vsm, const float* __restrict__ wtk,
  const float* __restrict__ lsp, float* __restrict__ interw)
{
  __shared__ __align__(16) char smem[52224];
  __shared__ float red[8];
  __shared__ float wtkS[52];
  const int c = blockIdx.x, b = blockIdx.y;
  const int t = threadIdx.x, lane = t&63, wid = t>>6;

  if (t<50) wtkS[t] = wtk[b*50+t];
  if (t<64){
    const float* a = AG + (size_t)b*512 + t*8;
    const float* m = RMN + (size_t)c*512 + t*8;
    float4 a0=*(const float4*)a, a1=*(const float4*)(a+4);
    float4 m0=*(const float4*)m, m1=*(const float4*)(m+4);
    float s = a0.x*m0.x+a0.y*m0.y+a0.z*m0.z+a0.w*m0.w + a1.x*m1.x+a1.y*m1.y+a1.z*m1.z+a1.w*m1.w;
    s = wave_sum(s);
    if (t==0) red[4] = s;
  }

  f32x4 acc[4][4];
  #pragma unroll
  for (int i=0;i<4;++i)
    #pragma unroll
    for (int j=0;j<4;++j) acc[i][j] = (f32x4){0.f,0.f,0.f,0.f};

  int offA[4], offB[4];
  #pragma unroll
  for (int mt=0; mt<4; ++mt){
    int row = wid*64 + mt*16 + (lane&15);
    int sp = (lane>>4) ^ ((row>>1)&3);
    offA[mt] = row*64 + sp*16;
  }
  #pragma unroll
  for (int nt=0; nt<4; ++nt){
    int row = nt*16 + (lane&15);
    int sp = (lane>>4) ^ ((row>>1)&3);
    offB[nt] = row*64 + sp*16;
  }

  const unsigned short* Abase = ALbf + ((size_t)b<<17);
  const unsigned short* Bbase = RNbf + ((size_t)c<<15);

  auto STAGE = [&](int buf, int ks){
    const int Ab = buf? 20480 : 0, Bb = buf? 36864 : 16384;
    #pragma unroll
    for (int i=0;i<4;++i){
      int q = i*256 + t;
      int row = q>>2, sl = q&3;
      int slog = sl ^ ((row>>1)&3);
      gld16(Abase + ((size_t)row<<9) + ks*32 + slog*8, smem + Ab + (i*256 + wid*64)*16);
    }
    {
      int row = t>>2, sl = t&3;
      int slog = sl ^ ((row>>1)&3);
      gld16(Bbase + ((size_t)row<<9) + ks*32 + slog*8, smem + Bb + (wid*64)*16);
    }
  };

  STAGE(0, 0);
  __syncthreads();
  for (int ks=0; ks<16; ++ks){
    const int cur = ks&1;
    if (ks<15) STAGE(cur^1, ks+1);
    const int Ab = cur? 20480 : 0, Bb = cur? 36864 : 16384;
    short8v af[4], bf[4];
    #pragma unroll
    for (int mt=0; mt<4; ++mt) af[mt] = *(short8v*)(smem + Ab + offA[mt]);
    #pragma unroll
    for (int nt=0; nt<4; ++nt) bf[nt] = *(short8v*)(smem + Bb + offB[nt]);
    #pragma unroll
    for (int mt=0; mt<4; ++mt)
      #pragma unroll
      for (int nt=0; nt<4; ++nt)
        acc[mt][nt] = __builtin_amdgcn_mfma_f32_16x16x32_bf16(af[mt], bf[nt], acc[mt][nt], 0,0,0);
    __syncthreads();
  }

  #pragma unroll
  for (int mt=0; mt<4; ++mt){
    #pragma unroll
    for (int nt=0; nt<4; ++nt){
      int n = nt*16 + (lane&15);
      if (n < 51){
        int p0 = wid*64 + mt*16 + (lane>>4)*4;
        int addr = ((n<<10) + (p0<<2)) ^ ((((n&7)^wid)&7)<<4);
        *(f32x4*)(smem + addr) = acc[mt][nt];
      }
    }
  }
  __syncthreads();

  const int n = wid*16 + (lane>>2);
  const int q = lane&3;
  float v[64];
  if (n < 51){
    #pragma unroll
    for (int i=0;i<16;++i){
      int p = q*64 + i*4;
      int addr = ((n<<10) + (p<<2)) ^ ((((n&7)^q)&7)<<4);
      *(f32x4*)&v[i*4] = *(f32x4*)(smem + addr);
    }
  } else {
    #pragma unroll
    for (int i=0;i<64;++i) v[i] = -INFINITY;
  }
  if (q==3){
    #pragma unroll
    for (int j=4;j<64;++j) v[j] = -INFINITY;
  }

  #pragma unroll
  for (int k=2;k<=64;k<<=1){
    #pragma unroll
    for (int j=k>>1;j>=1;j>>=1){
      #pragma unroll
      for (int i=0;i<64;++i){
        if ((i&j)==0){
          int p2 = i|j;
          float a=v[i], bb=v[p2];
          if ((i&k)!=0){ v[i]=fminf(a,bb); v[p2]=fmaxf(a,bb); }
          else         { v[i]=fmaxf(a,bb); v[p2]=fminf(a,bb); }
        }
      }
    }
  }
  #pragma unroll
  for (int i=0;i<32;++i){
    float pa = dppf<0xB1>(v[63-i]);
    float pb = dppf<0xB1>(v[i]);
    v[i]    = fmaxf(v[i], pa);
    v[63-i] = fmaxf(v[63-i], pb);
  }
  #pragma unroll
  for (int j=32;j>=1;j>>=1){
    #pragma unroll
    for (int i=0;i<64;++i){
      if ((i&j)==0){ int p2=i|j; float a=v[i],bb=v[p2]; v[i]=fmaxf(a,bb); v[p2]=fminf(a,bb); }
    }
  }
  #pragma unroll
  for (int i=0;i<32;++i){
    float pa = dppf<0x4E>(v[63-i]);
    float pb = dppf<0x4E>(v[i]);
    v[i]    = fmaxf(v[i], pa);
    v[63-i] = fmaxf(v[63-i], pb);
  }
  #pragma unroll
  for (int j=32;j>=1;j>>=1){
    #pragma unroll
    for (int i=0;i<64;++i){
      if ((i&j)==0){ int p2=i|j; float a=v[i],bb=v[p2]; v[i]=fmaxf(a,bb); v[p2]=fminf(a,bb); }
    }
  }

  float s = 0.f;
  #pragma unroll
  for (int r=0;r<50;++r) s = fmaf(wtkS[r], v[r], s);
  float val = (q==0 && n<51) ? vsm[c*51+n]*s : 0.f;
  val = wave_sum(val);
  if (lane==0) red[wid] = val;
  __syncthreads();
  if (t==0){
    float ls = expf(lsp[0]);
    interw[b*100+c] = ls*(red[4] + red[0]+red[1]+red[2]+red[3]);
  }
}

// ---------- cache top-50 selection + rbar (bf16 hi/lo out), chunked gather ----------
__global__ __launch_bounds__(256) void k_cache_sel(const float* __restrict__ cdot, const float* __restrict__ norm2,
                                                   const float* __restrict__ raw,
                                                   unsigned short* __restrict__ rbH, unsigned short* __restrict__ rbL){
  __shared__ int idxL[50];
  __shared__ float invL[50];
  int i = blockIdx.x, t = threadIdx.x;
  if (t < 64){
    int lane = t;
    float v[4];
    #pragma unroll
    for (int s2=0;s2<4;++s2){
      int p = lane+64*s2;
      v[s2] = (p<196)? cdot[(size_t)i*196+p] * (1.f/sqrtf(norm2[(size_t)i*196+p])) : -INFINITY;
    }
    for (int k=0;k<50;++k){
      unsigned long long best = pkvi(v[0], lane);
      { unsigned long long cc=pkvi(v[1],lane+64);  if(cc>best)best=cc; }
      { unsigned long long cc=pkvi(v[2],lane+128); if(cc>best)best=cc; }
      { unsigned long long cc=pkvi(v[3],lane+192); if(cc>best)best=cc; }
      best = wave_max_ull(best);
      int widx = (int)(0xffffffffu - (unsigned)(best & 0xffffffffu));
      if (lane==0){ idxL[k]=widx; invL[k] = 1.f/sqrtf(norm2[(size_t)i*196+widx]); }
      if ((widx&63)==lane) v[widx>>6] = -INFINITY;
    }
  }
  __syncthreads();
  float a0=0.f, a1=0.f;
  #pragma unroll
  for (int kc=0; kc<5; ++kc){
    float x0[10], x1[10];
    #pragma unroll
    for (int j=0;j<10;++j){
      const float* rp = raw + ((size_t)i*196 + idxL[kc*10+j])*512;
      x0[j] = rp[t]; x1[j] = rp[t+256];
    }
    #pragma unroll
    for (int j=0;j<10;++j){
      float iv = invL[kc*10+j];
      a0 = fmaf(x0[j], iv, a0);
      a1 = fmaf(x1[j], iv, a1);
    }
  }
  unsigned short h0 = f2bf(a0), h1 = f2bf(a1);
  rbH[(size_t)i*512+t]     = h0;  rbL[(size_t)i*512+t]     = f2bf(a0 - bf2f(h0));
  rbH[(size_t)i*512+t+256] = h1;  rbL[(size_t)i*512+t+256] = f2bf(a1 - bf2f(h1));
}

// ---------- affinity ----------
__global__ __launch_bounds__(256) void k_aff(const float* __restrict__ qk, const float* __restrict__ ck, float* __restrict__ aff){
  int gid = blockIdx.x*4 + (threadIdx.x>>6);
  int lane = threadIdx.x&63;
  int b = gid/800, i = gid%800;
  const float* a = qk + (size_t)b*512 + lane*8;
  const float* v = ck + (size_t)i*512 + lane*8;
  float4 a0=*(const float4*)a, a1=*(const float4*)(a+4);
  float4 v0=*(const float4*)v, v1=*(const float4*)(v+4);
  float s = a0.x*v0.x+a0.y*v0.y+a0.z*v0.z+a0.w*v0.w + a1.x*v1.x+a1.y*v1.y+a1.z*v1.z+a1.w*v1.w;
  s = wave_sum(s);
  if (lane==0) aff[gid] = expf(-5.5f*(1.f - s));
}

// ---------- intra = aff @ cache_values ----------
__global__ __launch_bounds__(128) void k_intra(const float* __restrict__ aff, const float* __restrict__ cv, float* __restrict__ intra){
  __shared__ float affL[800];
  int b = blockIdx.x, t = threadIdx.x;
  for (int f=t; f<800; f+=128) affL[f] = aff[b*800+f];
  __syncthreads();
  if (t<100){
    float s=0.f;
    for (int i=0;i<800;++i) s = fmaf(affL[i], cv[(size_t)i*100+t], s);
    intra[b*100+t]=s;
  }
}

// ---------- final combine ----------
__global__ void k_final(const float* __restrict__ interw, const float* __restrict__ intraw,
                        const float* __restrict__ lsp, const float* __restrict__ esp, float* __restrict__ outp){
  int idx = blockIdx.x*256 + threadIdx.x;
  if (idx < 3200){
    float ls = expf(lsp[0]);
    float sc = 1.f/(1.f + expf(-esp[0]));
    float iv = interw[idx], ia = intraw[idx];
    outp[idx]        = iv*(1.f-sc) + ia*ls*sc;
    outp[3200+idx]   = iv;
    outp[6400+idx]   = ia;
  }
}

extern "C" void kernel_launch(void* const* d_in, const int* in_sizes, int n_in,
                              void* d_out, int out_size, void* d_ws, size_t ws_size,
                              hipStream_t stream)
{
  (void)in_sizes; (void)n_in; (void)out_size; (void)ws_size;
  const float* lf   = (const float*)d_in[0];
  const float* Wa   = (const float*)d_in[1];
  const float* tc   = (const float*)d_in[2];
  const float* Wq   = (const float*)d_in[3];
  const float* Wk   = (const float*)d_in[4];
  const float* Wv   = (const float*)d_in[5];
  const float* Wo   = (const float*)d_in[6];
  const float* ln1g = (const float*)d_in[7];
  const float* ln1b = (const float*)d_in[8];
  const float* ln2g = (const float*)d_in[9];
  const float* ln2b = (const float*)d_in[10];
  const float* W1   = (const float*)d_in[11];
  const float* b1   = (const float*)d_in[12];
  const float* W2   = (const float*)d_in[13];
  const float* b2   = (const float*)d_in[14];
  const float* lsp  = (const float*)d_in[15];
  const float* esp  = (const float*)d_in[16];
  const float* raw  = (const float*)d_in[17];
  const float* cv   = (const float*)d_in[18];
  const int* labels = (const int*)d_in[19];
  const int* clab   = (const int*)d_in[20];

  float* out = (float*)d_out;
  float* outAG = out + 9600;
  float* outTK = out + 25984;
  float* outBK = out + 845184;
  float* outRN = out + 1664384;

  float* wsf = (float*)d_ws;
  size_t o = 0;
  #define WALLOC(name, n) float* name = wsf + o; o += (size_t)(n);
  WALLOC(AL,    6272*512)
  WALLOC(xb,    1632*512)
  WALLOC(qb,    1632*512)
  WALLOC(kb,    1600*512)
  WALLOC(vbuf,  1600*512)
  WALLOC(x2,    1632*512)
  WALLOC(TB,    1632*512)
  WALLOC(btm,   100*512)
  WALLOC(zm,    100*512)
  WALLOC(RMN,   100*512)
  WALLOC(vsm,   5100)
  WALLOC(st,    6272)
  WALLOC(wbp,   6272)
  WALLOC(sLw,   6272)
  WALLOC(AGw,   32*512)
  WALLOC(qkb,   32*512)
  WALLOC(wtk,   1600)
  WALLOC(norm2, 156800)
  WALLOC(cdot,  156800)
  WALLOC(mbuf,  800*512)
  WALLOC(ckb,   800*512)
  WALLOC(aff,   25600)
  WALLOC(interw,3200)
  WALLOC(intraw,3200)
  #undef WALLOC
  int* tki = (int*)(wsf + o); o += 1600;
  int* bki = (int*)(wsf + o); o += 1600;
  unsigned short* ALbf = (unsigned short*)(wsf + o); o += (size_t)32*256*512/2;
  unsigned short* RNbf = (unsigned short*)(wsf + o); o += (size_t)100*64*512/2;
  #define WALLOC16(name, n) unsigned short* name = (unsigned short*)(wsf + o); o += ((size_t)(n)+1)/2;
  WALLOC16(waHi, 262144)  WALLOC16(waLo, 262144)
  WALLOC16(wqHi, 262144)  WALLOC16(wqLo, 262144)
  WALLOC16(wkHi, 262144)  WALLOC16(wkLo, 262144)
  WALLOC16(wvHi, 262144)  WALLOC16(wvLo, 262144)
  WALLOC16(woHi, 262144)  WALLOC16(woLo, 262144)
  WALLOC16(w1Hi, 1048576) WALLOC16(w1Lo, 1048576)
  WALLOC16(w2Hi, 1048576) WALLOC16(w2Lo, 1048576)
  WALLOC16(dfrag, 262144)
  WALLOC16(ln1H, 851968)  WALLOC16(ln1L, 851968)   // 1664*512
  WALLOC16(h2H,  851968)  WALLOC16(h2L,  851968)
  WALLOC16(obH,  851968)  WALLOC16(obL,  851968)
  WALLOC16(tkH,  851968)  WALLOC16(tkL,  851968)
  WALLOC16(y1H,  3407872) WALLOC16(y1L,  3407872)  // 1664*2048
  WALLOC16(rbH,  458752)  WALLOC16(rbL,  458752)   // 896*512
  WALLOC16(lfH,  3211264) WALLOC16(lfL,  3211264)  // 6272*512
  #undef WALLOC16

  // weight pre-conversions + D(frag) + lf hi/lo
  k_convw<false,false><<<dim3(512), dim3(256), 0, stream>>>(Wa, waHi, waLo, 512,512);
  k_convw4<<<dim3(512,4), dim3(256), 0, stream>>>(Wq,Wk,Wv,Wo, wqHi,wqLo, wkHi,wkLo, wvHi,wvLo, woHi,woLo);
  k_convw<true ,false><<<dim3(2048), dim3(256), 0, stream>>>(W1, w1Hi, w1Lo, 512,2048);
  k_convw<true ,false><<<dim3(512), dim3(256), 0, stream>>>(W2, w2Hi, w2Lo, 2048,512);
  k_convd2<<<dim3(512), dim3(256), 0, stream>>>(Wa, dfrag);
  k_convw<false,false><<<dim3(6272), dim3(256), 0, stream>>>(lf, lfH, lfL, 6272,512);

  // ALbf and RNbf are adjacent: one memset
  hipMemsetAsync(ALbf, 0, ((size_t)32*256*512 + (size_t)100*64*512)*2, stream);

  // adapted_local = norm(local_feat @ Wa^T)  (3-split MFMA)
  gemmAB<0><<<dim3(49,4), dim3(256), 0, stream>>>(lfH, lfL, waHi, waLo, AL, nullptr, nullptr, 6272,512,512, nullptr, nullptr);
  k_rownorm<<<dim3(6272), dim3(256), 0, stream>>>(AL, AL, ALbf, 6272);
  k_meanrows_norm<<<dim3(32), dim3(256), 0, stream>>>(AL, 196, AGw, outAG);
  k_meanrows_norm<<<dim3(100), dim3(256), 0, stream>>>(tc, 51, btm, (float*)nullptr);
  k_zmat<<<dim3(100), dim3(256), 0, stream>>>(btm, Wa, zm);
  // sim_target + topk/botk + gathers
  k_dot_bp<<<dim3(1568), dim3(256), 0, stream>>>(AL, btm, labels, st, 0);
  k_topbot<<<dim3(32), dim3(64), 0, stream>>>(st, tki, bki);
  k_gather_tb<<<dim3(32), dim3(256), 0, stream>>>(AL, tki, bki, outTK, outBK, qkb, tkH, tkL);
  // bonder (pre-converted-A MFMA GEMMs)
  k_gxln<<<dim3(1632), dim3(256), 0, stream>>>(tc, labels, ln1g, ln1b, xb, ln1H, ln1L);
  gemmABQKV<<<dim3(13,4,3), dim3(256), 0, stream>>>(ln1H,ln1L, tkH,tkL, wqHi,wqLo, wkHi,wkLo, wvHi,wvLo, qb, kb, vbuf);
  k_attn2<<<dim3(32,8), dim3(256), 0, stream>>>(qb, kb, vbuf, obH, obL);
  gemmAB<4><<<dim3(13,4), dim3(256), 0, stream>>>(obH, obL, woHi, woLo, x2, nullptr, nullptr, 1632,512,512, nullptr, xb);
  k_layernorm2<<<dim3(1632), dim3(256), 0, stream>>>(x2, h2H, h2L, ln2g, ln2b);
  gemmAB<11><<<dim3(13,16), dim3(256), 0, stream>>>(h2H, h2L, w1Hi, w1Lo, nullptr, y1H, y1L, 1632,2048,512, b1, nullptr);
  gemmAB<5><<<dim3(13,4), dim3(256), 0, stream>>>(y1H, y1L, w2Hi, w2Lo, TB, nullptr, nullptr, 1632,512,2048, b2, x2);
  // refined text (+ bf16 padded copy)
  k_refined<<<dim3(5100), dim3(256), 0, stream>>>(tc, TB, labels, outRN, RNbf);
  k_meanrows_norm<<<dim3(100), dim3(256), 0, stream>>>(outRN, 51, RMN, (float*)nullptr);
  k_vsm<<<dim3(100), dim3(256), 0, stream>>>(outRN, RMN, vsm);
  // dense logits
  k_dot2<<<dim3(1568), dim3(256), 0, stream>>>(AL, AGw, outRN, wbp, sLw);
  k_wtopk<<<dim3(32), dim3(64), 0, stream>>>(sLw, wbp, wtk);
  k_dense3<<<dim3(100,32), dim3(256), 0, stream>>>(ALbf, RNbf, RMN, AGw, vsm, wtk, lsp, interw);
  // cache path: ks-interleaved stage||MFMA k_un7
  k_un7<<<dim3(1225), dim3(512), 0, stream>>>(raw, dfrag, zm, clab, cdot, norm2);
  k_cache_sel<<<dim3(800), dim3(256), 0, stream>>>(cdot, norm2, raw, rbH, rbL);
  gemmAB<0><<<dim3(7,4), dim3(256), 0, stream>>>(rbH, rbL, waHi, waLo, mbuf, nullptr, nullptr, 800,512,512, nullptr, nullptr);
  k_rownorm<<<dim3(800), dim3(256), 0, stream>>>(mbuf, ckb, (unsigned short*)nullptr, 800);
  k_aff<<<dim3(6400), dim3(256), 0, stream>>>(qkb, ckb, aff);
  k_intra<<<dim3(32), dim3(128), 0, stream>>>(aff, cv, intraw);
  k_final<<<dim3(13), dim3(256), 0, stream>>>(interw, intraw, lsp, esp, out);
}

// Round 17
// 980.960 us; speedup vs baseline: 1.1121x; 1.1121x over previous
//
#include <hip/hip_runtime.h>
#include <math.h>

#define DEV static __device__ __forceinline__

typedef __attribute__((ext_vector_type(8))) short short8v;
typedef __attribute__((ext_vector_type(8))) _Float16 half8v;
typedef __attribute__((ext_vector_type(4))) float f32x4;

// ---------- helpers ----------
DEV unsigned encf(float f){ unsigned b=__float_as_uint(f); return b ^ (0x80000000u | (unsigned)((int)b>>31)); }
DEV unsigned long long pkvi(float v, int idx){
  return ((unsigned long long)encf(v)<<32) | (unsigned long long)(0xffffffffu - (unsigned)idx);
}
DEV unsigned long long wave_max_ull(unsigned long long u){
  #pragma unroll
  for (int m=1;m<64;m<<=1){ unsigned long long o = __shfl_xor(u, m); if (o>u) u=o; }
  return u;
}
DEV float wave_sum(float v){
  #pragma unroll
  for (int m=32;m;m>>=1) v += __shfl_xor(v, m);
  return v;
}
DEV float blk_sum256(float v, float* scr){
  v = wave_sum(v);
  __syncthreads();
  if ((threadIdx.x & 63)==0) scr[threadIdx.x>>6] = v;
  __syncthreads();
  return scr[0]+scr[1]+scr[2]+scr[3];
}
DEV float gelu_f(float x){ return 0.5f*x*(1.f + tanhf(0.7978845608028654f*(x + 0.044715f*x*x*x))); }
DEV unsigned short f2bf(float x){
  unsigned u = __float_as_uint(x);
  unsigned r = (u + 0x7fffu + ((u>>16)&1u)) >> 16;
  return (unsigned short)r;
}
DEV float bf2f(unsigned short h){ return __uint_as_float(((unsigned)h)<<16); }
DEV void gld16(const void* g, void* l){
  __builtin_amdgcn_global_load_lds((const __attribute__((address_space(1))) unsigned int*)g,
                                   (__attribute__((address_space(3))) unsigned int*)l, 16, 0, 0);
}
template<int CTRL>
DEV float dppf(float x){
  return __int_as_float(__builtin_amdgcn_mov_dpp(__float_as_int(x), CTRL, 0xF, 0xF, false));
}

// ---------- weight pre-conversion: fp32 W[R][C] -> bf16 hi/lo [n][k] ----------
template<bool TRANS, bool SUBI>
__global__ __launch_bounds__(256) void k_convw(const float* __restrict__ W,
    unsigned short* __restrict__ hi, unsigned short* __restrict__ lo, int R, int C){
  int n = blockIdx.x;
  int K = TRANS ? R : C;
  for (int k = threadIdx.x; k < K; k += 256){
    float x = TRANS ? W[(size_t)k*C + n] : W[(size_t)n*C + k];
    if (SUBI && k==n) x -= 1.f;
    unsigned short h = f2bf(x);
    hi[(size_t)n*K + k] = h;
    if (lo) lo[(size_t)n*K + k] = f2bf(x - bf2f(h));
  }
}

// ---------- fused conversion of 4 transposed 512x512 weights ----------
__global__ __launch_bounds__(256) void k_convw4(
  const float* __restrict__ Wq, const float* __restrict__ Wk,
  const float* __restrict__ Wv, const float* __restrict__ Wo,
  unsigned short* __restrict__ qh, unsigned short* __restrict__ ql,
  unsigned short* __restrict__ kh, unsigned short* __restrict__ kl,
  unsigned short* __restrict__ vh, unsigned short* __restrict__ vl,
  unsigned short* __restrict__ oh, unsigned short* __restrict__ ol)
{
  int n = blockIdx.x;
  const float* W; unsigned short *hi, *lo;
  switch(blockIdx.y){
    case 0: W=Wq; hi=qh; lo=ql; break;
    case 1: W=Wk; hi=kh; lo=kl; break;
    case 2: W=Wv; hi=vh; lo=vl; break;
    default: W=Wo; hi=oh; lo=ol; break;
  }
  for (int k = threadIdx.x; k < 512; k += 256){
    float x = W[(size_t)k*512 + n];
    unsigned short h = f2bf(x);
    hi[(size_t)n*512 + k] = h;
    lo[(size_t)n*512 + k] = f2bf(x - bf2f(h));
  }
}

// ---------- D = Wa - I as f16 in MFMA-fragment-major layout ----------
__global__ __launch_bounds__(256) void k_convd2(const float* __restrict__ Wa, unsigned short* __restrict__ Dfrag){
  int e = blockIdx.x;
  int tile = e>>4, lr = e&15;
  for (int d = threadIdx.x; d < 512; d += 256){
    float x = Wa[(size_t)e*512 + d] - (e==d ? 1.f : 0.f);
    union { _Float16 hh; unsigned short u; } cv;
    cv.hh = (_Float16)x;
    int ks = d>>5, q = (d>>3)&3, el = d&7;
    Dfrag[(size_t)(((tile*16+ks)*64 + q*16 + lr)*8 + el)] = cv.u;
  }
}

// ---------- gemmAB: both operands pre-converted bf16 hi/lo, gld16 staging ----------
// EPI bits: 1=+bias[n], 2=gelu, 4=+resid fp32, 8=write hi/lo (else fp32)
template<int EPI>
__global__ __launch_bounds__(256,2) void gemmAB(
  const unsigned short* __restrict__ Ahi, const unsigned short* __restrict__ Alo,
  const unsigned short* __restrict__ Bhi, const unsigned short* __restrict__ Blo,
  float* __restrict__ Cp, unsigned short* __restrict__ Chi, unsigned short* __restrict__ Clo,
  const int M, const int N, const int K,
  const float* __restrict__ bias, const float* __restrict__ resid)
{
  __shared__ __align__(16) char sm[32768];
  const int t = threadIdx.x, lane = t&63, wid = t>>6;
  const int row0 = blockIdx.x*128, col0 = blockIdx.y*128;
  f32x4 acc[2][8];
  #pragma unroll
  for (int i=0;i<2;++i)
    #pragma unroll
    for (int j=0;j<8;++j) acc[i][j] = (f32x4){0.f,0.f,0.f,0.f};

  int offA[2], offB[8];
  #pragma unroll
  for (int mt=0; mt<2; ++mt){
    int row = (2*wid+mt)*16 + (lane&15);
    int sp = (lane>>4) ^ ((row>>1)&3);
    offA[mt] = row*64 + sp*16;
  }
  #pragma unroll
  for (int nt=0; nt<8; ++nt){
    int row = nt*16 + (lane&15);
    int sp = (lane>>4) ^ ((row>>1)&3);
    offB[nt] = row*64 + sp*16;
  }

  const int nks = K >> 5;
  for (int ks=0; ks<nks; ++ks){
    #pragma unroll
    for (int i=0;i<2;++i){
      int s = i*256 + t, row = s>>2, sl2 = s&3, slog = sl2 ^ ((row>>1)&3);
      size_t ga = (size_t)(row0+row)*K + ks*32 + slog*8;
      size_t gb = (size_t)(col0+row)*K + ks*32 + slog*8;
      int dst = (i*256 + wid*64)*16;
      gld16(Ahi + ga, sm + dst);
      gld16(Alo + ga, sm + 8192 + dst);
      gld16(Bhi + gb, sm + 16384 + dst);
      gld16(Blo + gb, sm + 24576 + dst);
    }
    __syncthreads();
    short8v ah0 = *(short8v*)(sm + offA[0]);
    short8v ah1 = *(short8v*)(sm + offA[1]);
    short8v al0 = *(short8v*)(sm + 8192 + offA[0]);
    short8v al1 = *(short8v*)(sm + 8192 + offA[1]);
    #pragma unroll
    for (int nt=0; nt<8; ++nt){
      short8v bh = *(short8v*)(sm + 16384 + offB[nt]);
      short8v bl = *(short8v*)(sm + 24576 + offB[nt]);
      acc[0][nt] = __builtin_amdgcn_mfma_f32_16x16x32_bf16(ah0, bh, acc[0][nt], 0,0,0);
      acc[0][nt] = __builtin_amdgcn_mfma_f32_16x16x32_bf16(ah0, bl, acc[0][nt], 0,0,0);
      acc[0][nt] = __builtin_amdgcn_mfma_f32_16x16x32_bf16(al0, bh, acc[0][nt], 0,0,0);
      acc[1][nt] = __builtin_amdgcn_mfma_f32_16x16x32_bf16(ah1, bh, acc[1][nt], 0,0,0);
      acc[1][nt] = __builtin_amdgcn_mfma_f32_16x16x32_bf16(ah1, bl, acc[1][nt], 0,0,0);
      acc[1][nt] = __builtin_amdgcn_mfma_f32_16x16x32_bf16(al1, bh, acc[1][nt], 0,0,0);
    }
    __syncthreads();
  }

  #pragma unroll
  for (int mt=0; mt<2; ++mt){
    #pragma unroll
    for (int nt=0; nt<8; ++nt){
      int n = col0 + nt*16 + (lane&15);
      int mb = row0 + (2*wid+mt)*16 + (lane>>4)*4;
      #pragma unroll
      for (int j=0;j<4;++j){
        int m = mb + j;
        if (m < M){
          float v = acc[mt][nt][j];
          if (EPI & 1) v += bias[n];
          if (EPI & 2) v = gelu_f(v);
          if (EPI & 4) v += resid[(size_t)m*N + n];
          if (EPI & 8){
            unsigned short h = f2bf(v);
            Chi[(size_t)m*N + n] = h;
            Clo[(size_t)m*N + n] = f2bf(v - bf2f(h));
          } else {
            Cp[(size_t)m*N + n] = v;
          }
        }
      }
    }
  }
}

// ---------- fused QKV on pre-converted A (z selector) ----------
__global__ __launch_bounds__(256,2) void gemmABQKV(
  const unsigned short* __restrict__ lnH, const unsigned short* __restrict__ lnL,
  const unsigned short* __restrict__ tkH, const unsigned short* __restrict__ tkL,
  const unsigned short* __restrict__ qh, const unsigned short* __restrict__ ql,
  const unsigned short* __restrict__ kh, const unsigned short* __restrict__ kl,
  const unsigned short* __restrict__ vh, const unsigned short* __restrict__ vl,
  float* __restrict__ qb, float* __restrict__ kb, float* __restrict__ vbuf)
{
  __shared__ __align__(16) char sm[32768];
  const int z = blockIdx.z;
  const unsigned short* Ahi = (z==0)? lnH : tkH;
  const unsigned short* Alo = (z==0)? lnL : tkL;
  const unsigned short* Bhi = (z==0)? qh : (z==1? kh : vh);
  const unsigned short* Blo = (z==0)? ql : (z==1? kl : vl);
  float* Cp = (z==0)? qb : (z==1? kb : vbuf);
  const int M = (z==0)? 1632 : 1600;
  const int K = 512, N = 512;
  const int t = threadIdx.x, lane = t&63, wid = t>>6;
  const int row0 = blockIdx.x*128, col0 = blockIdx.y*128;
  f32x4 acc[2][8];
  #pragma unroll
  for (int i=0;i<2;++i)
    #pragma unroll
    for (int j=0;j<8;++j) acc[i][j] = (f32x4){0.f,0.f,0.f,0.f};

  int offA[2], offB[8];
  #pragma unroll
  for (int mt=0; mt<2; ++mt){
    int row = (2*wid+mt)*16 + (lane&15);
    int sp = (lane>>4) ^ ((row>>1)&3);
    offA[mt] = row*64 + sp*16;
  }
  #pragma unroll
  for (int nt=0; nt<8; ++nt){
    int row = nt*16 + (lane&15);
    int sp = (lane>>4) ^ ((row>>1)&3);
    offB[nt] = row*64 + sp*16;
  }

  for (int ks=0; ks<16; ++ks){
    #pragma unroll
    for (int i=0;i<2;++i){
      int s = i*256 + t, row = s>>2, sl2 = s&3, slog = sl2 ^ ((row>>1)&3);
      size_t ga = (size_t)(row0+row)*K + ks*32 + slog*8;
      size_t gb = (size_t)(col0+row)*K + ks*32 + slog*8;
      int dst = (i*256 + wid*64)*16;
      gld16(Ahi + ga, sm + dst);
      gld16(Alo + ga, sm + 8192 + dst);
      gld16(Bhi + gb, sm + 16384 + dst);
      gld16(Blo + gb, sm + 24576 + dst);
    }
    __syncthreads();
    short8v ah0 = *(short8v*)(sm + offA[0]);
    short8v ah1 = *(short8v*)(sm + offA[1]);
    short8v al0 = *(short8v*)(sm + 8192 + offA[0]);
    short8v al1 = *(short8v*)(sm + 8192 + offA[1]);
    #pragma unroll
    for (int nt=0; nt<8; ++nt){
      short8v bh = *(short8v*)(sm + 16384 + offB[nt]);
      short8v bl = *(short8v*)(sm + 24576 + offB[nt]);
      acc[0][nt] = __builtin_amdgcn_mfma_f32_16x16x32_bf16(ah0, bh, acc[0][nt], 0,0,0);
      acc[0][nt] = __builtin_amdgcn_mfma_f32_16x16x32_bf16(ah0, bl, acc[0][nt], 0,0,0);
      acc[0][nt] = __builtin_amdgcn_mfma_f32_16x16x32_bf16(al0, bh, acc[0][nt], 0,0,0);
      acc[1][nt] = __builtin_amdgcn_mfma_f32_16x16x32_bf16(ah1, bh, acc[1][nt], 0,0,0);
      acc[1][nt] = __builtin_amdgcn_mfma_f32_16x16x32_bf16(ah1, bl, acc[1][nt], 0,0,0);
      acc[1][nt] = __builtin_amdgcn_mfma_f32_16x16x32_bf16(al1, bh, acc[1][nt], 0,0,0);
    }
    __syncthreads();
  }

  #pragma unroll
  for (int mt=0; mt<2; ++mt){
    #pragma unroll
    for (int nt=0; nt<8; ++nt){
      int n = col0 + nt*16 + (lane&15);
      int mb = row0 + (2*wid+mt)*16 + (lane>>4)*4;
      #pragma unroll
      for (int j=0;j<4;++j){
        int m = mb + j;
        if (m < M) Cp[(size_t)m*N + n] = acc[mt][nt][j];
      }
    }
  }
}

// ---------- cache path v11: 64-row tile, 2 blocks/CU for cross-block phase overlap ----------
__global__ __launch_bounds__(512,4) void k_un7(
  const float* __restrict__ raw, const unsigned short* __restrict__ Dfrag,
  const float* __restrict__ zm, const int* __restrict__ clab,
  float* __restrict__ cdot, float* __restrict__ norm2)
{
  __shared__ __align__(16) char Alds[65536];
  __shared__ float n2sq[64];
  __shared__ float n2x[4][64];
  const int t = threadIdx.x, lane = t&63;
  const int wid = t>>6, wm = wid>>2, wn = wid&3;
  const int m0 = blockIdx.x*64;

  // ---- phase 1: 8 threads/row; each covers one K-half (8 ks) x 8 floats; chunked loads ----
  {
    const int row = t>>3, s3 = t&7;
    const int sl = s3&3, kh = s3>>2;
    const int slg = sl ^ ((row>>1)&3);
    const float* rp = raw + ((size_t)(m0+row))*512 + kh*256 + slg*8;
    const float* zp = zm + (size_t)clab[(m0+row)/196]*512 + kh*256 + slg*8;
    float sq=0.f, cd=0.f;
    #pragma unroll
    for (int c4=0; c4<2; ++c4){
      float4 pr[8], pz[8];
      #pragma unroll
      for (int i=0;i<4;++i){
        pr[2*i]   = *(const float4*)(rp + (c4*4+i)*32);
        pr[2*i+1] = *(const float4*)(rp + (c4*4+i)*32 + 4);
      }
      #pragma unroll
      for (int i=0;i<4;++i){
        pz[2*i]   = *(const float4*)(zp + (c4*4+i)*32);
        pz[2*i+1] = *(const float4*)(zp + (c4*4+i)*32 + 4);
      }
      #pragma unroll
      for (int i=0;i<4;++i){
        int ks = kh*8 + c4*4 + i;
        float xs[8] = {pr[2*i].x,pr[2*i].y,pr[2*i].z,pr[2*i].w,
                       pr[2*i+1].x,pr[2*i+1].y,pr[2*i+1].z,pr[2*i+1].w};
        float zs[8] = {pz[2*i].x,pz[2*i].y,pz[2*i].z,pz[2*i].w,
                       pz[2*i+1].x,pz[2*i+1].y,pz[2*i+1].z,pz[2*i+1].w};
        union { _Float16 h[8]; f32x4 f; } uh;
        #pragma unroll
        for (int u=0;u<8;++u){
          uh.h[u] = (_Float16)xs[u];
          sq = fmaf(xs[u],xs[u],sq);
          cd = fmaf(xs[u],zs[u],cd);
        }
        *(f32x4*)(Alds + ks*4096 + row*64 + sl*16) = uh.f;
      }
    }
    sq += __shfl_xor(sq,1); sq += __shfl_xor(sq,2); sq += __shfl_xor(sq,4);
    cd += __shfl_xor(cd,1); cd += __shfl_xor(cd,2); cd += __shfl_xor(cd,4);
    if (s3==0){ n2sq[row] = sq; cdot[m0+row] = cd; }
  }
  __syncthreads();

  int offA[2];
  #pragma unroll
  for (int mt=0; mt<2; ++mt){
    int r2 = wm*32 + mt*16 + (lane&15);
    int sp = (lane>>4) ^ ((r2>>1)&3);
    offA[mt] = r2*64 + sp*16;
  }
  const half8v* Dv = (const half8v*)Dfrag;

  float pacc[2][4];
  #pragma unroll
  for (int a_=0;a_<2;++a_)
    #pragma unroll
    for (int b_=0;b_<4;++b_) pacc[a_][b_]=0.f;

  // ---- phase 2: e-loop, barrier-free ----
  for (int eb2=0; eb2<4; ++eb2){
    f32x4 acc[2][2];
    #pragma unroll
    for (int a_=0;a_<2;++a_)
      #pragma unroll
      for (int b_=0;b_<2;++b_) acc[a_][b_] = (f32x4){0.f,0.f,0.f,0.f};

    #pragma unroll 4
    for (int ks=0; ks<16; ++ks){
      half8v af[2], bf[2];
      #pragma unroll
      for (int mt=0; mt<2; ++mt) af[mt] = *(half8v*)(Alds + ks*4096 + offA[mt]);
      #pragma unroll
      for (int nt=0; nt<2; ++nt) bf[nt] = Dv[(size_t)(((eb2*8 + wn*2 + nt)*16 + ks)*64 + lane)];
      #pragma unroll
      for (int mt=0; mt<2; ++mt)
        #pragma unroll
        for (int nt=0; nt<2; ++nt)
          acc[mt][nt] = __builtin_amdgcn_mfma_f32_16x16x32_f16(af[mt], bf[nt], acc[mt][nt], 0,0,0);
    }

    #pragma unroll
    for (int mt=0; mt<2; ++mt){
      #pragma unroll
      for (int j=0;j<4;++j){
        int row2 = wm*32 + mt*16 + (lane>>4)*4 + j;
        float p = 0.f;
        #pragma unroll
        for (int nt=0; nt<2; ++nt){
          float U = acc[mt][nt][j];
          int eg = eb2*128 + wn*32 + nt*16 + (lane&15);
          int kse = eg>>5, o = eg&31;
          int sll = (o>>3) ^ ((row2>>1)&3);
          float rh = (float)*(const _Float16*)(Alds + kse*4096 + row2*64 + sll*16 + (o&7)*2);
          p = fmaf(U, 2.f*rh + U, p);
        }
        p += __shfl_xor(p,1); p += __shfl_xor(p,2); p += __shfl_xor(p,4); p += __shfl_xor(p,8);
        pacc[mt][j] += p;
      }
    }
  }

  // ---- phase 3: combine across wn waves, single deterministic write ----
  __syncthreads();
  if ((lane&15)==0){
    #pragma unroll
    for (int mt=0; mt<2; ++mt)
      #pragma unroll
      for (int j=0;j<4;++j)
        n2x[wn][wm*32 + mt*16 + (lane>>4)*4 + j] = pacc[mt][j];
  }
  __syncthreads();
  if (t < 64)
    norm2[m0+t] = n2sq[t] + n2x[0][t] + n2x[1][t] + n2x[2][t] + n2x[3][t];
}

// ---------- row normalize (512 cols), optional bf16 dual-write ----------
__global__ __launch_bounds__(256) void k_rownorm(const float* __restrict__ in, float* __restrict__ out,
                                                 unsigned short* __restrict__ bfo, int nrows){
  __shared__ float scr[4];
  int r = blockIdx.x, t = threadIdx.x; (void)nrows;
  const float* p = in + (size_t)r*512;
  float x0 = p[t], x1 = p[t+256];
  float ss = blk_sum256(x0*x0 + x1*x1, scr);
  float inv = 1.f/sqrtf(ss);
  float v0 = x0*inv, v1 = x1*inv;
  out[(size_t)r*512 + t] = v0;
  out[(size_t)r*512 + t + 256] = v1;
  if (bfo){
    size_t br = (size_t)(r/196)*256 + (r%196);
    bfo[br*512 + t]     = f2bf(v0);
    bfo[br*512 + t+256] = f2bf(v1);
  }
}

// ---------- mean over consecutive rows, then normalize ----------
__global__ __launch_bounds__(256) void k_meanrows_norm(const float* __restrict__ in, int nper,
                                                       float* __restrict__ o1, float* __restrict__ o2){
  __shared__ float scr[4];
  int g = blockIdx.x, t = threadIdx.x;
  float s0=0.f, s1=0.f;
  const float* bp = in + (size_t)g*nper*512;
  for (int r=0;r<nper;++r){ s0 += bp[(size_t)r*512+t]; s1 += bp[(size_t)r*512+t+256]; }
  float ss = blk_sum256(s0*s0+s1*s1, scr);
  float inv = 1.f/sqrtf(ss);
  float v0 = s0*inv, v1 = s1*inv;
  o1[(size_t)g*512+t]=v0; o1[(size_t)g*512+t+256]=v1;
  if (o2){ o2[(size_t)g*512+t]=v0; o2[(size_t)g*512+t+256]=v1; }
}

// ---------- z = btm @ Wa ----------
__global__ __launch_bounds__(256) void k_zmat(const float* __restrict__ btm, const float* __restrict__ Wa, float* __restrict__ z){
  int c = blockIdx.x, t = threadIdx.x;
  float a0=0.f, a1=0.f;
  for (int d=0; d<512; ++d){
    float bv = btm[c*512+d];
    a0 = fmaf(bv, Wa[(size_t)d*512+t], a0);
    a1 = fmaf(bv, Wa[(size_t)d*512+t+256], a1);
  }
  z[c*512+t]=a0; z[c*512+t+256]=a1;
}

// ---------- per-(b,p) row dot with a per-b 512-vector ----------
__global__ __launch_bounds__(256) void k_dot_bp(const float* __restrict__ AL, const float* __restrict__ vecs,
                                                const int* __restrict__ sel, float* __restrict__ outv, int mode){
  int wid = blockIdx.x*4 + (threadIdx.x>>6);
  int lane = threadIdx.x & 63;
  int b = wid/196;
  int vrow = sel ? sel[b] : (mode ? 0 : b);
  const float* a = AL + (size_t)wid*512 + lane*8;
  const float* v = vecs + (size_t)vrow*512 + lane*8;
  float4 a0 = *(const float4*)a, a1 = *(const float4*)(a+4);
  float4 v0 = *(const float4*)v, v1 = *(const float4*)(v+4);
  float s = a0.x*v0.x + a0.y*v0.y + a0.z*v0.z + a0.w*v0.w
          + a1.x*v1.x + a1.y*v1.y + a1.z*v1.z + a1.w*v1.w;
  s = wave_sum(s);
  if (lane==0) outv[wid] = s;
}

// ---------- fused dual dot ----------
__global__ __launch_bounds__(256) void k_dot2(const float* __restrict__ AL, const float* __restrict__ AGw,
                                              const float* __restrict__ RN00,
                                              float* __restrict__ wbp, float* __restrict__ sLw){
  int wid = blockIdx.x*4 + (threadIdx.x>>6);
  int lane = threadIdx.x & 63;
  int b = wid/196;
  const float* a = AL + (size_t)wid*512 + lane*8;
  const float* v = AGw + (size_t)b*512 + lane*8;
  const float* w = RN00 + lane*8;
  float4 a0=*(const float4*)a, a1=*(const float4*)(a+4);
  float4 v0=*(const float4*)v, v1=*(const float4*)(v+4);
  float4 w0=*(const float4*)w, w1=*(const float4*)(w+4);
  float s1 = a0.x*v0.x+a0.y*v0.y+a0.z*v0.z+a0.w*v0.w + a1.x*v1.x+a1.y*v1.y+a1.z*v1.z+a1.w*v1.w;
  float s2 = a0.x*w0.x+a0.y*w0.y+a0.z*w0.z+a0.w*w0.w + a1.x*w1.x+a1.y*w1.y+a1.z*w1.z+a1.w*w1.w;
  s1 = wave_sum(s1); s2 = wave_sum(s2);
  if (lane==0){ wbp[wid] = s1; sLw[wid] = s2; }
}

// ---------- sorted top-50 and bottom-50 indices of st[b,:196] ----------
__global__ __launch_bounds__(64) void k_topbot(const float* __restrict__ st, int* __restrict__ tki, int* __restrict__ bki){
  int b = blockIdx.x, lane = threadIdx.x;
  float v[4];
  #pragma unroll
  for (int s2=0;s2<4;++s2){ int p = lane + 64*s2; v[s2] = (p<196)? st[b*196+p] : -INFINITY; }
  for (int k=0;k<50;++k){
    unsigned long long best = pkvi(v[0], lane);
    { unsigned long long cc=pkvi(v[1],lane+64);  if(cc>best)best=cc; }
    { unsigned long long cc=pkvi(v[2],lane+128); if(cc>best)best=cc; }
    { unsigned long long cc=pkvi(v[3],lane+192); if(cc>best)best=cc; }
    best = wave_max_ull(best);
    int widx = (int)(0xffffffffu - (unsigned)(best & 0xffffffffu));
    if (lane==0) tki[b*50+k] = widx;
    if ((widx & 63)==lane) v[widx>>6] = -INFINITY;
  }
  #pragma unroll
  for (int s2=0;s2<4;++s2){ int p = lane + 64*s2; v[s2] = (p<196)? -st[b*196+p] : -INFINITY; }
  for (int k=0;k<50;++k){
    unsigned long long best = pkvi(v[0], lane);
    { unsigned long long cc=pkvi(v[1],lane+64);  if(cc>best)best=cc; }
    { unsigned long long cc=pkvi(v[2],lane+128); if(cc>best)best=cc; }
    { unsigned long long cc=pkvi(v[3],lane+192); if(cc>best)best=cc; }
    best = wave_max_ull(best);
    int widx = (int)(0xffffffffu - (unsigned)(best & 0xffffffffu));
    if (lane==0) bki[b*50+k] = widx;
    if ((widx & 63)==lane) v[widx>>6] = -INFINITY;
  }
}

// ---------- gather topk/botk feats (+ bf16 hi/lo of topk), query_keys ----------
__global__ __launch_bounds__(256) void k_gather_tb(const float* __restrict__ AL, const int* __restrict__ tki, const int* __restrict__ bki,
                                                   float* __restrict__ otk, float* __restrict__ obk, float* __restrict__ qk,
                                                   unsigned short* __restrict__ tkH, unsigned short* __restrict__ tkL){
  __shared__ float scr[4];
  int b = blockIdx.x, t = threadIdx.x;
  float a0=0.f, a1=0.f;
  for (int k=0;k<50;++k){
    int pt = tki[b*50+k];
    const float* rp = AL + ((size_t)b*196+pt)*512;
    float x0 = rp[t], x1 = rp[t+256];
    size_t ro = ((size_t)b*50+k)*512;
    otk[ro + t] = x0; otk[ro + t+256] = x1;
    unsigned short h0 = f2bf(x0), h1 = f2bf(x1);
    tkH[ro + t] = h0;      tkL[ro + t]     = f2bf(x0 - bf2f(h0));
    tkH[ro + t+256] = h1;  tkL[ro + t+256] = f2bf(x1 - bf2f(h1));
    a0 += x0; a1 += x1;
    int pb = bki[b*50+k];
    const float* rb = AL + ((size_t)b*196+pb)*512;
    obk[ro + t] = rb[t]; obk[ro + t+256] = rb[t+256];
  }
  float ss = blk_sum256(a0*a0+a1*a1, scr);
  float inv = 1.f/sqrtf(ss);
  qk[b*512+t] = a0*inv; qk[b*512+t+256] = a1*inv;
}

// ---------- fused gather x = text_cache[labels] + layernorm -> xb fp32, ln1 hi/lo ----------
__global__ __launch_bounds__(256) void k_gxln(const float* __restrict__ tc, const int* __restrict__ labels,
                                              const float* __restrict__ g, const float* __restrict__ be,
                                              float* __restrict__ xb,
                                              unsigned short* __restrict__ hi, unsigned short* __restrict__ lo){
  __shared__ float scr[4];
  int r = blockIdx.x, t = threadIdx.x;
  int b = r/51, n = r%51;
  int lab = labels[b];
  const float* src = tc + ((size_t)lab*51 + n)*512;
  float x0 = src[t], x1 = src[t+256];
  xb[(size_t)r*512+t] = x0; xb[(size_t)r*512+t+256] = x1;
  float s = blk_sum256(x0+x1, scr);
  float mean = s*(1.f/512.f);
  float ss = blk_sum256(x0*x0+x1*x1, scr);
  float var = ss*(1.f/512.f) - mean*mean;
  float inv = 1.f/sqrtf(var + 1e-5f);
  float v0 = (x0-mean)*inv*g[t]     + be[t];
  float v1 = (x1-mean)*inv*g[t+256] + be[t+256];
  unsigned short h0 = f2bf(v0), h1 = f2bf(v1);
  hi[(size_t)r*512+t]     = h0;  lo[(size_t)r*512+t]     = f2bf(v0 - bf2f(h0));
  hi[(size_t)r*512+t+256] = h1;  lo[(size_t)r*512+t+256] = f2bf(v1 - bf2f(h1));
}

// ---------- layernorm over 512, bf16 hi/lo output ----------
__global__ __launch_bounds__(256) void k_layernorm2(const float* __restrict__ in,
                                                    unsigned short* __restrict__ hi, unsigned short* __restrict__ lo,
                                                    const float* __restrict__ g, const float* __restrict__ be){
  __shared__ float scr[4];
  int r = blockIdx.x, t = threadIdx.x;
  const float* p = in + (size_t)r*512;
  float x0=p[t], x1=p[t+256];
  float s = blk_sum256(x0+x1, scr);
  float mean = s*(1.f/512.f);
  float ss = blk_sum256(x0*x0+x1*x1, scr);
  float var = ss*(1.f/512.f) - mean*mean;
  float inv = 1.f/sqrtf(var + 1e-5f);
  float v0 = (x0-mean)*inv*g[t]     + be[t];
  float v1 = (x1-mean)*inv*g[t+256] + be[t+256];
  unsigned short h0 = f2bf(v0), h1 = f2bf(v1);
  hi[(size_t)r*512+t]     = h0;  lo[(size_t)r*512+t]     = f2bf(v0 - bf2f(h0));
  hi[(size_t)r*512+t+256] = h1;  lo[(size_t)r*512+t+256] = f2bf(v1 - bf2f(h1));
}

// ---------- bonder attention, bf16 hi/lo output ----------
__global__ __launch_bounds__(256) void k_attn2(const float* __restrict__ qb, const float* __restrict__ kb,
                                               const float* __restrict__ vb,
                                               unsigned short* __restrict__ obH, unsigned short* __restrict__ obL){
  int b = blockIdx.x, h = blockIdx.y, t = threadIdx.x;
  __shared__ float qh[51][65];
  __shared__ float kh[50][65];
  __shared__ float vh[50][65];
  __shared__ float S[51][52];
  for (int f=t; f<51*64; f+=256){ int n=f>>6, d=f&63; qh[n][d] = qb[((size_t)(b*51+n))*512 + h*64 + d]; }
  for (int f=t; f<50*64; f+=256){ int m=f>>6, d=f&63;
    kh[m][d] = kb[((size_t)(b*50+m))*512 + h*64 + d];
    vh[m][d] = vb[((size_t)(b*50+m))*512 + h*64 + d];
  }
  __syncthreads();
  for (int f=t; f<51*50; f+=256){
    int n=f/50, m=f%50;
    float s=0.f;
    #pragma unroll 8
    for (int d=0; d<64; ++d) s = fmaf(qh[n][d], kh[m][d], s);
    S[n][m] = s*0.125f;
  }
  __syncthreads();
  int w = t>>6, lane = t&63;
  for (int n=w; n<51; n+=4){
    float x = (lane<50)? S[n][lane] : -INFINITY;
    float mx = x;
    #pragma unroll
    for (int m2=32;m2;m2>>=1) mx = fmaxf(mx, __shfl_xor(mx,m2));
    float e = (lane<50)? expf(x-mx) : 0.f;
    float se = wave_sum(e);
    if (lane<50) S[n][lane] = e/se;
  }
  __syncthreads();
  for (int f=t; f<51*64; f+=256){
    int n=f>>6, d=f&63;
    float s=0.f;
    #pragma unroll 10
    for (int m=0;m<50;++m) s = fmaf(S[n][m], vh[m][d], s);
    size_t idx = ((size_t)(b*51+n))*512 + h*64 + d;
    unsigned short hh = f2bf(s);
    obH[idx] = hh; obL[idx] = f2bf(s - bf2f(hh));
  }
}

// ---------- refined_norm row (c,n), dual-write bf16 padded ----------
__global__ __launch_bounds__(256) void k_refined(const float* __restrict__ tc, const float* __restrict__ TB,
                                                 const int* __restrict__ labels, float* __restrict__ RN,
                                                 unsigned short* __restrict__ RNbf){
  __shared__ float scr[4];
  __shared__ int labL[32];
  int blk = blockIdx.x, t = threadIdx.x;
  int c = blk/51, n = blk%51;
  if (t<32) labL[t] = labels[t];
  __syncthreads();
  float r0=0.f, r1=0.f;
  for (int b=0;b<32;++b){
    if (labL[b]==c){
      const float* tb = TB + ((size_t)(b*51+n))*512;
      r0 += tb[t]; r1 += tb[t+256];
    }
  }
  const float* tcp = tc + ((size_t)(c*51+n))*512;
  r0 = tcp[t]     + r0*(1.f/64.f);
  r1 = tcp[t+256] + r1*(1.f/64.f);
  float ss = blk_sum256(r0*r0+r1*r1, scr);
  float inv = 1.f/sqrtf(ss);
  float v0 = r0*inv, v1 = r1*inv;
  RN[((size_t)(c*51+n))*512+t]     = v0;
  RN[((size_t)(c*51+n))*512+t+256] = v1;
  size_t br = (size_t)c*64 + n;
  RNbf[br*512 + t]     = f2bf(v0);
  RNbf[br*512 + t+256] = f2bf(v1);
}

// ---------- v softmax ----------
__global__ __launch_bounds__(256) void k_vsm(const float* __restrict__ RN, const float* __restrict__ RMN, float* __restrict__ vsm){
  __shared__ float sv[51];
  int c = blockIdx.x, t = threadIdx.x, w = t>>6, lane = t&63;
  for (int n=w; n<51; n+=4){
    const float* a = RN + ((size_t)(c*51+n))*512 + lane*8;
    const float* m = RMN + (size_t)c*512 + lane*8;
    float4 a0=*(const float4*)a, a1=*(const float4*)(a+4);
    float4 m0=*(const float4*)m, m1=*(const float4*)(m+4);
    float s = a0.x*m0.x+a0.y*m0.y+a0.z*m0.z+a0.w*m0.w + a1.x*m1.x+a1.y*m1.y+a1.z*m1.z+a1.w*m1.w;
    s = wave_sum(s);
    if (lane==0) sv[n]=s;
  }
  __syncthreads();
  if (t<64){
    float x = (t<51)? sv[t] : -INFINITY;
    float mx = x;
    #pragma unroll
    for (int m2=32;m2;m2>>=1) mx = fmaxf(mx, __shfl_xor(mx,m2));
    float e = (t<51)? expf(x-mx) : 0.f;
    float se = wave_sum(e);
    if (t<51) vsm[c*51+t] = e/se;
  }
}

// ---------- idx_w -> w_topk per b ----------
__global__ __launch_bounds__(64) void k_wtopk(const float* __restrict__ sLg,
                                              const float* __restrict__ wbp, float* __restrict__ wtk){
  __shared__ int idxL[50];
  int b = blockIdx.x, lane = threadIdx.x;
  float v[4];
  #pragma unroll
  for (int s2=0;s2<4;++s2){ int p = lane+64*s2; v[s2] = (p<196)? sLg[b*196+p] : -INFINITY; }
  for (int k=0;k<50;++k){
    unsigned long long best = pkvi(v[0], lane);
    { unsigned long long cc=pkvi(v[1],lane+64);  if(cc>best)best=cc; }
    { unsigned long long cc=pkvi(v[2],lane+128); if(cc>best)best=cc; }
    { unsigned long long cc=pkvi(v[3],lane+192); if(cc>best)best=cc; }
    best = wave_max_ull(best);
    int widx = (int)(0xffffffffu - (unsigned)(best & 0xffffffffu));
    if (lane==0) idxL[k]=widx;
    if ((widx&63)==lane) v[widx>>6] = -INFINITY;
  }
  __syncthreads();
  float wv = (lane<50)? wbp[b*196 + idxL[lane]] : -INFINITY;
  float mx = wv;
  #pragma unroll
  for (int m2=32;m2;m2>>=1) mx = fmaxf(mx, __shfl_xor(mx,m2));
  float e = (lane<50)? expf(wv-mx) : 0.f;
  float se = wave_sum(e);
  if (lane<50) wtk[b*50+lane] = e/se;
}

// ---------- dense logits v3: dbuf MFMA GEMM + register bitonic top-50 ----------
__global__ __launch_bounds__(256,3) void k_dense3(
  const unsigned short* __restrict__ ALbf, const unsigned short* __restrict__ RNbf,
  const float* __restrict__ RMN, const float* __restrict__ AG,
  const float* __restrict__ vsm, const float* __restrict__ wtk,
  const float* __restrict__ lsp, float* __restrict__ interw)
{
  __shared__ __align__(16) char smem[52224];
  __shared__ float red[8];
  __shared__ float wtkS[52];
  const int c = blockIdx.x, b = blockIdx.y;
  const int t = threadIdx.x, lane = t&63, wid = t>>6;

  if (t<50) wtkS[t] = wtk[b*50+t];
  if (t<64){
    const float* a = AG + (size_t)b*512 + t*8;
    const float* m = RMN + (size_t)c*512 + t*8;
    float4 a0=*(const float4*)a, a1=*(const float4*)(a+4);
    float4 m0=*(const float4*)m, m1=*(const float4*)(m+4);
    float s = a0.x*m0.x+a0.y*m0.y+a0.z*m0.z+a0.w*m0.w + a1.x*m1.x+a1.y*m1.y+a1.z*m1.z+a1.w*m1.w;
    s = wave_sum(s);
    if (t==0) red[4] = s;
  }

  f32x4 acc[4][4];
  #pragma unroll
  for (int i=0;i<4;++i)
    #pragma unroll
    for (int j=0;j<4;++j) acc[i][j] = (f32x4){0.f,0.f,0.f,0.f};

  int offA[4], offB[4];
  #pragma unroll
  for (int mt=0; mt<4; ++mt){
    int row = wid*64 + mt*16 + (lane&15);
    int sp = (lane>>4) ^ ((row>>1)&3);
    offA[mt] = row*64 + sp*16;
  }
  #pragma unroll
  for (int nt=0; nt<4; ++nt){
    int row = nt*16 + (lane&15);
    int sp = (lane>>4) ^ ((row>>1)&3);
    offB[nt] = row*64 + sp*16;
  }

  const unsigned short* Abase = ALbf + ((size_t)b<<17);
  const unsigned short* Bbase = RNbf + ((size_t)c<<15);

  auto STAGE = [&](int buf, int ks){
    const int Ab = buf? 20480 : 0, Bb = buf? 36864 : 16384;
    #pragma unroll
    for (int i=0;i<4;++i){
      int q = i*256 + t;
      int row = q>>2, sl = q&3;
      int slog = sl ^ ((row>>1)&3);
      gld16(Abase + ((size_t)row<<9) + ks*32 + slog*8, smem + Ab + (i*256 + wid*64)*16);
    }
    {
      int row = t>>2, sl = t&3;
      int slog = sl ^ ((row>>1)&3);
      gld16(Bbase + ((size_t)row<<9) + ks*32 + slog*8, smem + Bb + (wid*64)*16);
    }
  };

  STAGE(0, 0);
  __syncthreads();
  for (int ks=0; ks<16; ++ks){
    const int cur = ks&1;
    if (ks<15) STAGE(cur^1, ks+1);
    const int Ab = cur? 20480 : 0, Bb = cur? 36864 : 16384;
    short8v af[4], bf[4];
    #pragma unroll
    for (int mt=0; mt<4; ++mt) af[mt] = *(short8v*)(smem + Ab + offA[mt]);
    #pragma unroll
    for (int nt=0; nt<4; ++nt) bf[nt] = *(short8v*)(smem + Bb + offB[nt]);
    #pragma unroll
    for (int mt=0; mt<4; ++mt)
      #pragma unroll
      for (int nt=0; nt<4; ++nt)
        acc[mt][nt] = __builtin_amdgcn_mfma_f32_16x16x32_bf16(af[mt], bf[nt], acc[mt][nt], 0,0,0);
    __syncthreads();
  }

  #pragma unroll
  for (int mt=0; mt<4; ++mt){
    #pragma unroll
    for (int nt=0; nt<4; ++nt){
      int n = nt*16 + (lane&15);
      if (n < 51){
        int p0 = wid*64 + mt*16 + (lane>>4)*4;
        int addr = ((n<<10) + (p0<<2)) ^ ((((n&7)^wid)&7)<<4);
        *(f32x4*)(smem + addr) = acc[mt][nt];
      }
    }
  }
  __syncthreads();

  const int n = wid*16 + (lane>>2);
  const int q = lane&3;
  float v[64];
  if (n < 51){
    #pragma unroll
    for (int i=0;i<16;++i){
      int p = q*64 + i*4;
      int addr = ((n<<10) + (p<<2)) ^ ((((n&7)^q)&7)<<4);
      *(f32x4*)&v[i*4] = *(f32x4*)(smem + addr);
    }
  } else {
    #pragma unroll
    for (int i=0;i<64;++i) v[i] = -INFINITY;
  }
  if (q==3){
    #pragma unroll
    for (int j=4;j<64;++j) v[j] = -INFINITY;
  }

  #pragma unroll
  for (int k=2;k<=64;k<<=1){
    #pragma unroll
    for (int j=k>>1;j>=1;j>>=1){
      #pragma unroll
      for (int i=0;i<64;++i){
        if ((i&j)==0){
          int p2 = i|j;
          float a=v[i], bb=v[p2];
          if ((i&k)!=0){ v[i]=fminf(a,bb); v[p2]=fmaxf(a,bb); }
          else         { v[i]=fmaxf(a,bb); v[p2]=fminf(a,bb); }
        }
      }
    }
  }
  #pragma unroll
  for (int i=0;i<32;++i){
    float pa = dppf<0xB1>(v[63-i]);
    float pb = dppf<0xB1>(v[i]);
    v[i]    = fmaxf(v[i], pa);
    v[63-i] = fmaxf(v[63-i], pb);
  }
  #pragma unroll
  for (int j=32;j>=1;j>>=1){
    #pragma unroll
    for (int i=0;i<64;++i){
      if ((i&j)==0){ int p2=i|j; float a=v[i],bb=v[p2]; v[i]=fmaxf(a,bb); v[p2]=fminf(a,bb); }
    }
  }
  #pragma unroll
  for (int i=0;i<32;++i){
    float pa = dppf<0x4E>(v[63-i]);
    float pb = dppf<0x4E>(v[i]);
    v[i]    = fmaxf(v[i], pa);
    v[63-i] = fmaxf(v[63-i], pb);
  }
  #pragma unroll
  for (int j=32;j>=1;j>>=1){
    #pragma unroll
    for (int i=0;i<64;++i){
      if ((i&j)==0){ int p2=i|j; float a=v[i],bb=v[p2]; v[i]=fmaxf(a,bb); v[p2]=fminf(a,bb); }
    }
  }

  float s = 0.f;
  #pragma unroll
  for (int r=0;r<50;++r) s = fmaf(wtkS[r], v[r], s);
  float val = (q==0 && n<51) ? vsm[c*51+n]*s : 0.f;
  val = wave_sum(val);
  if (lane==0) red[wid] = val;
  __syncthreads();
  if (t==0){
    float ls = expf(lsp[0]);
    interw[b*100+c] = ls*(red[4] + red[0]+red[1]+red[2]+red[3]);
  }
}

// ---------- cache top-50 selection + rbar (bf16 hi/lo out), chunked gather ----------
__global__ __launch_bounds__(256) void k_cache_sel(const float* __restrict__ cdot, const float* __restrict__ norm2,
                                                   const float* __restrict__ raw,
                                                   unsigned short* __restrict__ rbH, unsigned short* __restrict__ rbL){
  __shared__ int idxL[50];
  __shared__ float invL[50];
  int i = blockIdx.x, t = threadIdx.x;
  if (t < 64){
    int lane = t;
    float v[4];
    #pragma unroll
    for (int s2=0;s2<4;++s2){
      int p = lane+64*s2;
      v[s2] = (p<196)? cdot[(size_t)i*196+p] * (1.f/sqrtf(norm2[(size_t)i*196+p])) : -INFINITY;
    }
    for (int k=0;k<50;++k){
      unsigned long long best = pkvi(v[0], lane);
      { unsigned long long cc=pkvi(v[1],lane+64);  if(cc>best)best=cc; }
      { unsigned long long cc=pkvi(v[2],lane+128); if(cc>best)best=cc; }
      { unsigned long long cc=pkvi(v[3],lane+192); if(cc>best)best=cc; }
      best = wave_max_ull(best);
      int widx = (int)(0xffffffffu - (unsigned)(best & 0xffffffffu));
      if (lane==0){ idxL[k]=widx; invL[k] = 1.f/sqrtf(norm2[(size_t)i*196+widx]); }
      if ((widx&63)==lane) v[widx>>6] = -INFINITY;
    }
  }
  __syncthreads();
  float a0=0.f, a1=0.f;
  #pragma unroll
  for (int kc=0; kc<5; ++kc){
    float x0[10], x1[10];
    #pragma unroll
    for (int j=0;j<10;++j){
      const float* rp = raw + ((size_t)i*196 + idxL[kc*10+j])*512;
      x0[j] = rp[t]; x1[j] = rp[t+256];
    }
    #pragma unroll
    for (int j=0;j<10;++j){
      float iv = invL[kc*10+j];
      a0 = fmaf(x0[j], iv, a0);
      a1 = fmaf(x1[j], iv, a1);
    }
  }
  unsigned short h0 = f2bf(a0), h1 = f2bf(a1);
  rbH[(size_t)i*512+t]     = h0;  rbL[(size_t)i*512+t]     = f2bf(a0 - bf2f(h0));
  rbH[(size_t)i*512+t+256] = h1;  rbL[(size_t)i*512+t+256] = f2bf(a1 - bf2f(h1));
}

// ---------- affinity ----------
__global__ __launch_bounds__(256) void k_aff(const float* __restrict__ qk, const float* __restrict__ ck, float* __restrict__ aff){
  int gid = blockIdx.x*4 + (threadIdx.x>>6);
  int lane = threadIdx.x&63;
  int b = gid/800, i = gid%800;
  const float* a = qk + (size_t)b*512 + lane*8;
  const float* v = ck + (size_t)i*512 + lane*8;
  float4 a0=*(const float4*)a, a1=*(const float4*)(a+4);
  float4 v0=*(const float4*)v, v1=*(const float4*)(v+4);
  float s = a0.x*v0.x+a0.y*v0.y+a0.z*v0.z+a0.w*v0.w + a1.x*v1.x+a1.y*v1.y+a1.z*v1.z+a1.w*v1.w;
  s = wave_sum(s);
  if (lane==0) aff[gid] = expf(-5.5f*(1.f - s));
}

// ---------- intra = aff @ cache_values ----------
__global__ __launch_bounds__(128) void k_intra(const float* __restrict__ aff, const float* __restrict__ cv, float* __restrict__ intra){
  __shared__ float affL[800];
  int b = blockIdx.x, t = threadIdx.x;
  for (int f=t; f<800; f+=128) affL[f] = aff[b*800+f];
  __syncthreads();
  if (t<100){
    float s=0.f;
    for (int i=0;i<800;++i) s = fmaf(affL[i], cv[(size_t)i*100+t], s);
    intra[b*100+t]=s;
  }
}

// ---------- final combine ----------
__global__ void k_final(const float* __restrict__ interw, const float* __restrict__ intraw,
                        const float* __restrict__ lsp, const float* __restrict__ esp, float* __restrict__ outp){
  int idx = blockIdx.x*256 + threadIdx.x;
  if (idx < 3200){
    float ls = expf(lsp[0]);
    float sc = 1.f/(1.f + expf(-esp[0]));
    float iv = interw[idx], ia = intraw[idx];
    outp[idx]        = iv*(1.f-sc) + ia*ls*sc;
    outp[3200+idx]   = iv;
    outp[6400+idx]   = ia;
  }
}

extern "C" void kernel_launch(void* const* d_in, const int* in_sizes, int n_in,
                              void* d_out, int out_size, void* d_ws, size_t ws_size,
                              hipStream_t stream)
{
  (void)in_sizes; (void)n_in; (void)out_size; (void)ws_size;
  const float* lf   = (const float*)d_in[0];
  const float* Wa   = (const float*)d_in[1];
  const float* tc   = (const float*)d_in[2];
  const float* Wq   = (const float*)d_in[3];
  const float* Wk   = (const float*)d_in[4];
  const float* Wv   = (const float*)d_in[5];
  const float* Wo   = (const float*)d_in[6];
  const float* ln1g = (const float*)d_in[7];
  const float* ln1b = (const float*)d_in[8];
  const float* ln2g = (const float*)d_in[9];
  const float* ln2b = (const float*)d_in[10];
  const float* W1   = (const float*)d_in[11];
  const float* b1   = (const float*)d_in[12];
  const float* W2   = (const float*)d_in[13];
  const float* b2   = (const float*)d_in[14];
  const float* lsp  = (const float*)d_in[15];
  const float* esp  = (const float*)d_in[16];
  const float* raw  = (const float*)d_in[17];
  const float* cv   = (const float*)d_in[18];
  const int* labels = (const int*)d_in[19];
  const int* clab   = (const int*)d_in[20];

  float* out = (float*)d_out;
  float* outAG = out + 9600;
  float* outTK = out + 25984;
  float* outBK = out + 845184;
  float* outRN = out + 1664384;

  float* wsf = (float*)d_ws;
  size_t o = 0;
  #define WALLOC(name, n) float* name = wsf + o; o += (size_t)(n);
  WALLOC(AL,    6272*512)
  WALLOC(xb,    1632*512)
  WALLOC(qb,    1632*512)
  WALLOC(kb,    1600*512)
  WALLOC(vbuf,  1600*512)
  WALLOC(x2,    1632*512)
  WALLOC(TB,    1632*512)
  WALLOC(btm,   100*512)
  WALLOC(zm,    100*512)
  WALLOC(RMN,   100*512)
  WALLOC(vsm,   5100)
  WALLOC(st,    6272)
  WALLOC(wbp,   6272)
  WALLOC(sLw,   6272)
  WALLOC(AGw,   32*512)
  WALLOC(qkb,   32*512)
  WALLOC(wtk,   1600)
  WALLOC(norm2, 156800)
  WALLOC(cdot,  156800)
  WALLOC(mbuf,  800*512)
  WALLOC(ckb,   800*512)
  WALLOC(aff,   25600)
  WALLOC(interw,3200)
  WALLOC(intraw,3200)
  #undef WALLOC
  int* tki = (int*)(wsf + o); o += 1600;
  int* bki = (int*)(wsf + o); o += 1600;
  unsigned short* ALbf = (unsigned short*)(wsf + o); o += (size_t)32*256*512/2;
  unsigned short* RNbf = (unsigned short*)(wsf + o); o += (size_t)100*64*512/2;
  #define WALLOC16(name, n) unsigned short* name = (unsigned short*)(wsf + o); o += ((size_t)(n)+1)/2;
  WALLOC16(waHi, 262144)  WALLOC16(waLo, 262144)
  WALLOC16(wqHi, 262144)  WALLOC16(wqLo, 262144)
  WALLOC16(wkHi, 262144)  WALLOC16(wkLo, 262144)
  WALLOC16(wvHi, 262144)  WALLOC16(wvLo, 262144)
  WALLOC16(woHi, 262144)  WALLOC16(woLo, 262144)
  WALLOC16(w1Hi, 1048576) WALLOC16(w1Lo, 1048576)
  WALLOC16(w2Hi, 1048576) WALLOC16(w2Lo, 1048576)
  WALLOC16(dfrag, 262144)
  WALLOC16(ln1H, 851968)  WALLOC16(ln1L, 851968)   // 1664*512
  WALLOC16(h2H,  851968)  WALLOC16(h2L,  851968)
  WALLOC16(obH,  851968)  WALLOC16(obL,  851968)
  WALLOC16(tkH,  851968)  WALLOC16(tkL,  851968)
  WALLOC16(y1H,  3407872) WALLOC16(y1L,  3407872)  // 1664*2048
  WALLOC16(rbH,  458752)  WALLOC16(rbL,  458752)   // 896*512
  WALLOC16(lfH,  3211264) WALLOC16(lfL,  3211264)  // 6272*512
  #undef WALLOC16

  // weight pre-conversions + D(frag) + lf hi/lo
  k_convw<false,false><<<dim3(512), dim3(256), 0, stream>>>(Wa, waHi, waLo, 512,512);
  k_convw4<<<dim3(512,4), dim3(256), 0, stream>>>(Wq,Wk,Wv,Wo, wqHi,wqLo, wkHi,wkLo, wvHi,wvLo, woHi,woLo);
  k_convw<true ,false><<<dim3(2048), dim3(256), 0, stream>>>(W1, w1Hi, w1Lo, 512,2048);
  k_convw<true ,false><<<dim3(512), dim3(256), 0, stream>>>(W2, w2Hi, w2Lo, 2048,512);
  k_convd2<<<dim3(512), dim3(256), 0, stream>>>(Wa, dfrag);
  k_convw<false,false><<<dim3(6272), dim3(256), 0, stream>>>(lf, lfH, lfL, 6272,512);

  // ALbf and RNbf are adjacent: one memset
  hipMemsetAsync(ALbf, 0, ((size_t)32*256*512 + (size_t)100*64*512)*2, stream);

  // adapted_local = norm(local_feat @ Wa^T)  (3-split MFMA)
  gemmAB<0><<<dim3(49,4), dim3(256), 0, stream>>>(lfH, lfL, waHi, waLo, AL, nullptr, nullptr, 6272,512,512, nullptr, nullptr);
  k_rownorm<<<dim3(6272), dim3(256), 0, stream>>>(AL, AL, ALbf, 6272);
  k_meanrows_norm<<<dim3(32), dim3(256), 0, stream>>>(AL, 196, AGw, outAG);
  k_meanrows_norm<<<dim3(100), dim3(256), 0, stream>>>(tc, 51, btm, (float*)nullptr);
  k_zmat<<<dim3(100), dim3(256), 0, stream>>>(btm, Wa, zm);
  // sim_target + topk/botk + gathers
  k_dot_bp<<<dim3(1568), dim3(256), 0, stream>>>(AL, btm, labels, st, 0);
  k_topbot<<<dim3(32), dim3(64), 0, stream>>>(st, tki, bki);
  k_gather_tb<<<dim3(32), dim3(256), 0, stream>>>(AL, tki, bki, outTK, outBK, qkb, tkH, tkL);
  // bonder (pre-converted-A MFMA GEMMs)
  k_gxln<<<dim3(1632), dim3(256), 0, stream>>>(tc, labels, ln1g, ln1b, xb, ln1H, ln1L);
  gemmABQKV<<<dim3(13,4,3), dim3(256), 0, stream>>>(ln1H,ln1L, tkH,tkL, wqHi,wqLo, wkHi,wkLo, wvHi,wvLo, qb, kb, vbuf);
  k_attn2<<<dim3(32,8), dim3(256), 0, stream>>>(qb, kb, vbuf, obH, obL);
  gemmAB<4><<<dim3(13,4), dim3(256), 0, stream>>>(obH, obL, woHi, woLo, x2, nullptr, nullptr, 1632,512,512, nullptr, xb);
  k_layernorm2<<<dim3(1632), dim3(256), 0, stream>>>(x2, h2H, h2L, ln2g, ln2b);
  gemmAB<11><<<dim3(13,16), dim3(256), 0, stream>>>(h2H, h2L, w1Hi, w1Lo, nullptr, y1H, y1L, 1632,2048,512, b1, nullptr);
  gemmAB<5><<<dim3(13,4), dim3(256), 0, stream>>>(y1H, y1L, w2Hi, w2Lo, TB, nullptr, nullptr, 1632,512,2048, b2, x2);
  // refined text (+ bf16 padded copy)
  k_refined<<<dim3(5100), dim3(256), 0, stream>>>(tc, TB, labels, outRN, RNbf);
  k_meanrows_norm<<<dim3(100), dim3(256), 0, stream>>>(outRN, 51, RMN, (float*)nullptr);
  k_vsm<<<dim3(100), dim3(256), 0, stream>>>(outRN, RMN, vsm);
  // dense logits
  k_dot2<<<dim3(1568), dim3(256), 0, stream>>>(AL, AGw, outRN, wbp, sLw);
  k_wtopk<<<dim3(32), dim3(64), 0, stream>>>(sLw, wbp, wtk);
  k_dense3<<<dim3(100,32), dim3(256), 0, stream>>>(ALbf, RNbf, RMN, AGw, vsm, wtk, lsp, interw);
  // cache path: 64-row tile k_un7, 2 blocks/CU
  k_un7<<<dim3(2450), dim3(512), 0, stream>>>(raw, dfrag, zm, clab, cdot, norm2);
  k_cache_sel<<<dim3(800), dim3(256), 0, stream>>>(cdot, norm2, raw, rbH, rbL);
  gemmAB<0><<<dim3(7,4), dim3(256), 0, stream>>>(rbH, rbL, waHi, waLo, mbuf, nullptr, nullptr, 800,512,512, nullptr, nullptr);
  k_rownorm<<<dim3(800), dim3(256), 0, stream>>>(mbuf, ckb, (unsigned short*)nullptr, 800);
  k_aff<<<dim3(6400), dim3(256), 0, stream>>>(qkb, ckb, aff);
  k_intra<<<dim3(32), dim3(128), 0, stream>>>(aff, cv, intraw);
  k_final<<<dim3(13), dim3(256), 0, stream>>>(interw, intraw, lsp, esp, out);
}